// Round 2
// baseline (1362.841 us; speedup 1.0000x reference)
//
#include <hip/hip_runtime.h>
#include <hip/hip_bf16.h>

#define NN 50000
#define EE 1600000
#define DIN 128
#define HH 256
#define DOUT 128

// ---------------- CSR build ----------------

__global__ __launch_bounds__(256) void hist_kernel(const int* __restrict__ dst, int* __restrict__ deg, int E) {
    int e = blockIdx.x * 256 + threadIdx.x;
    if (e < E) atomicAdd(&deg[dst[e]], 1);
}

#define SCAN_B 256

__global__ __launch_bounds__(SCAN_B) void scan1_kernel(const int* __restrict__ deg, int* __restrict__ exc,
                                                       int* __restrict__ bsum, int n) {
    __shared__ int tmp[SCAN_B];
    int i = blockIdx.x * SCAN_B + threadIdx.x;
    int v = (i < n) ? deg[i] : 0;
    tmp[threadIdx.x] = v;
    __syncthreads();
    for (int o = 1; o < SCAN_B; o <<= 1) {
        int t = (threadIdx.x >= o) ? tmp[threadIdx.x - o] : 0;
        __syncthreads();
        tmp[threadIdx.x] += t;
        __syncthreads();
    }
    if (i < n) exc[i] = tmp[threadIdx.x] - v;
    if (threadIdx.x == SCAN_B - 1) bsum[blockIdx.x] = tmp[SCAN_B - 1];
}

__global__ __launch_bounds__(SCAN_B) void scan2_kernel(int* __restrict__ bsum, int nb) {
    __shared__ int tmp[SCAN_B];
    int v = (threadIdx.x < nb) ? bsum[threadIdx.x] : 0;
    tmp[threadIdx.x] = v;
    __syncthreads();
    for (int o = 1; o < SCAN_B; o <<= 1) {
        int t = (threadIdx.x >= o) ? tmp[threadIdx.x - o] : 0;
        __syncthreads();
        tmp[threadIdx.x] += t;
        __syncthreads();
    }
    if (threadIdx.x < nb) bsum[threadIdx.x] = tmp[threadIdx.x] - v;
}

__global__ __launch_bounds__(SCAN_B) void scan3_kernel(int* __restrict__ exc, const int* __restrict__ bsum,
                                                       int* __restrict__ cursor, int n, int E) {
    int i = blockIdx.x * SCAN_B + threadIdx.x;
    if (i < n) {
        int v = exc[i] + bsum[blockIdx.x];
        exc[i] = v;
        cursor[i] = v;
    }
    if (i == n) exc[n] = E;
}

__global__ __launch_bounds__(256) void scatter_kernel(const int* __restrict__ src, const int* __restrict__ dst,
                                                      int* __restrict__ cursor, int* __restrict__ es, int E) {
    int e = blockIdx.x * 256 + threadIdx.x;
    if (e < E) {
        int d = dst[e];
        int pos = atomicAdd(&cursor[d], 1);
        es[pos] = src[e];
    }
}

// ---------------- fp32 GEMM: H = X @ W ----------------

__global__ __launch_bounds__(256) void gemm_kernel(const float* __restrict__ X, const float* __restrict__ W,
                                                   float* __restrict__ Hout, int n, int K, int Cout) {
    const int BM = 64, BN = 64, BK = 16;
    __shared__ float As[BK][BM + 1];
    __shared__ float Bs[BK][BN];
    int tid = threadIdx.x;
    int row0 = blockIdx.y * BM;
    int col0 = blockIdx.x * BN;
    int tx = tid % 16, ty = tid / 16;

    float acc[4][4];
#pragma unroll
    for (int i = 0; i < 4; ++i)
#pragma unroll
        for (int j = 0; j < 4; ++j) acc[i][j] = 0.f;

    int lm = tid / 4;
    int lk4 = (tid % 4) * 4;
    int lk = tid / 16;
    int ln4 = (tid % 16) * 4;

    for (int k0 = 0; k0 < K; k0 += BK) {
        float4 av = make_float4(0.f, 0.f, 0.f, 0.f);
        int gr = row0 + lm;
        if (gr < n) av = *(const float4*)(X + (size_t)gr * K + k0 + lk4);
        As[lk4 + 0][lm] = av.x;
        As[lk4 + 1][lm] = av.y;
        As[lk4 + 2][lm] = av.z;
        As[lk4 + 3][lm] = av.w;
        float4 bv = *(const float4*)(W + (size_t)(k0 + lk) * Cout + col0 + ln4);
        *(float4*)&Bs[lk][ln4] = bv;
        __syncthreads();
#pragma unroll
        for (int k = 0; k < BK; ++k) {
            float a0 = As[k][ty * 4 + 0], a1 = As[k][ty * 4 + 1];
            float a2 = As[k][ty * 4 + 2], a3 = As[k][ty * 4 + 3];
            float b0 = Bs[k][tx * 4 + 0], b1 = Bs[k][tx * 4 + 1];
            float b2 = Bs[k][tx * 4 + 2], b3 = Bs[k][tx * 4 + 3];
            acc[0][0] = fmaf(a0, b0, acc[0][0]); acc[0][1] = fmaf(a0, b1, acc[0][1]);
            acc[0][2] = fmaf(a0, b2, acc[0][2]); acc[0][3] = fmaf(a0, b3, acc[0][3]);
            acc[1][0] = fmaf(a1, b0, acc[1][0]); acc[1][1] = fmaf(a1, b1, acc[1][1]);
            acc[1][2] = fmaf(a1, b2, acc[1][2]); acc[1][3] = fmaf(a1, b3, acc[1][3]);
            acc[2][0] = fmaf(a2, b0, acc[2][0]); acc[2][1] = fmaf(a2, b1, acc[2][1]);
            acc[2][2] = fmaf(a2, b2, acc[2][2]); acc[2][3] = fmaf(a2, b3, acc[2][3]);
            acc[3][0] = fmaf(a3, b0, acc[3][0]); acc[3][1] = fmaf(a3, b1, acc[3][1]);
            acc[3][2] = fmaf(a3, b2, acc[3][2]); acc[3][3] = fmaf(a3, b3, acc[3][3]);
        }
        __syncthreads();
    }
#pragma unroll
    for (int i = 0; i < 4; ++i) {
        int r = row0 + ty * 4 + i;
        if (r < n) {
            float4 o = make_float4(acc[i][0], acc[i][1], acc[i][2], acc[i][3]);
            *(float4*)(Hout + (size_t)r * Cout + col0 + tx * 4) = o;
        }
    }
}

// ---------------- per-node attention logit dots ----------------

__global__ __launch_bounds__(256) void rowdots_kernel(const float* __restrict__ H, const float* __restrict__ a1,
                                                      const float* __restrict__ a2, float* __restrict__ s1,
                                                      float* __restrict__ s2, int n, int C) {
    int w = (blockIdx.x * 256 + threadIdx.x) >> 6;
    int lane = threadIdx.x & 63;
    if (w >= n) return;
    const float* hp = H + (size_t)w * C;
    float acc1 = 0.f, acc2 = 0.f;
    for (int c = lane; c < C; c += 64) {
        float hv = hp[c];
        acc1 = fmaf(hv, a1[c], acc1);
        acc2 = fmaf(hv, a2[c], acc2);
    }
#pragma unroll
    for (int o = 32; o; o >>= 1) {
        acc1 += __shfl_xor(acc1, o, 64);
        acc2 += __shfl_xor(acc2, o, 64);
    }
    if (lane == 0) {
        s1[w] = acc1;
        s2[w] = acc2;
    }
}

// ---------------- per-node softmax prep: alpha[e] = exp(lrelu(...) - m), invden[node] ----------------

__global__ __launch_bounds__(256) void mden_kernel(const float* __restrict__ ssrc, const float* __restrict__ sdst,
                                                   const int* __restrict__ off, const int* __restrict__ esrc,
                                                   float* __restrict__ alpha, float* __restrict__ invden, int n) {
    int w = (blockIdx.x * 256 + threadIdx.x) >> 6;
    int lane = threadIdx.x & 63;
    if (w >= n) return;
    int beg = off[w], end = off[w + 1];
    float sd = sdst[w];
    float m = -3e38f;
    for (int e = beg + lane; e < end; e += 64) {
        float v = ssrc[esrc[e]] + sd;
        v = (v > 0.f) ? v : 0.2f * v;
        alpha[e] = v;  // stash logit (coalesced), avoid re-gather in pass 2
        m = fmaxf(m, v);
    }
#pragma unroll
    for (int o = 32; o; o >>= 1) m = fmaxf(m, __shfl_xor(m, o, 64));
    float den = 0.f;
    for (int e = beg + lane; e < end; e += 64) {
        float p = __expf(alpha[e] - m);
        alpha[e] = p;
        den += p;
    }
#pragma unroll
    for (int o = 32; o; o >>= 1) den += __shfl_xor(den, o, 64);
    if (lane == 0) invden[w] = (den > 0.f) ? 1.f / den : 0.f;
}

// ---------------- aggregation: col-sliced, 64 cols per wave, 8-deep pipelined gather ----------------

template <int C, bool RELU, bool SOFTMAX>
__global__ __launch_bounds__(256) void aggc_kernel(const float* __restrict__ H, const float* __restrict__ alpha,
                                                   const float* __restrict__ invden, const int* __restrict__ off,
                                                   const int* __restrict__ esrc, const float* __restrict__ bias,
                                                   float* __restrict__ out, int n) {
    constexpr int WPN = C / 64;   // waves per node (4 for C=256, 2 for C=128)
    constexpr int NPB = 4 / WPN;  // nodes per block
    int wid = threadIdx.x >> 6, lane = threadIdx.x & 63;
    int node = blockIdx.x * NPB + wid / WPN;
    int wv = wid % WPN;
    int col = wv * 64 + lane;
    int beg = (node < n) ? off[node] : 0;
    int end = (node < n) ? off[node + 1] : 0;

    float acc = 0.f;
    for (int base = beg; base < end; base += 64) {
        int e = base + lane;
        float pl = 0.f;
        int sl = 0;
        if (e < end) {
            pl = alpha[e];
            sl = esrc[e];
        }
        int cnt = end - base;
        if (cnt > 64) cnt = 64;
        int j0 = 0;
        for (; j0 + 8 <= cnt; j0 += 8) {
            float pj[8];
            const float* hp[8];
#pragma unroll
            for (int u = 0; u < 8; ++u) {
                pj[u] = __shfl(pl, j0 + u, 64);
                int sj = __shfl(sl, j0 + u, 64);
                hp[u] = H + (size_t)sj * C + col;
            }
            float hv[8];
#pragma unroll
            for (int u = 0; u < 8; ++u) hv[u] = *hp[u];
#pragma unroll
            for (int u = 0; u < 8; ++u) acc = fmaf(pj[u], hv[u], acc);
        }
        for (; j0 < cnt; ++j0) {
            float pj = __shfl(pl, j0, 64);
            int sj = __shfl(sl, j0, 64);
            acc = fmaf(pj, H[(size_t)sj * C + col], acc);
        }
    }

    float ov = 0.f;
    if (node < n) {
        ov = fmaf(acc, invden[node], bias[col]);
        if (RELU) ov = fmaxf(ov, 0.f);
    }
    if (SOFTMAX) {
        // feature softmax across the node's WPN waves
        float mm = ov;
#pragma unroll
        for (int o = 32; o; o >>= 1) mm = fmaxf(mm, __shfl_xor(mm, o, 64));
        __shared__ float sred[4];
        if (lane == 0) sred[wid] = mm;
        __syncthreads();
        int bw = (wid / WPN) * WPN;
        mm = sred[bw];
#pragma unroll
        for (int u = 1; u < WPN; ++u) mm = fmaxf(mm, sred[bw + u]);
        float ex = __expf(ov - mm);
        float ss = ex;
#pragma unroll
        for (int o = 32; o; o >>= 1) ss += __shfl_xor(ss, o, 64);
        __syncthreads();
        if (lane == 0) sred[wid] = ss;
        __syncthreads();
        ss = 0.f;
#pragma unroll
        for (int u = 0; u < WPN; ++u) ss += sred[bw + u];
        ov = ex / ss;
    }
    if (node < n) out[(size_t)node * C + col] = ov;
}

// ---------------- launch ----------------

extern "C" void kernel_launch(void* const* d_in, const int* in_sizes, int n_in,
                              void* d_out, int out_size, void* d_ws, size_t ws_size,
                              hipStream_t stream) {
    const float* x = (const float*)d_in[0];
    const int* ei = (const int*)d_in[1];
    const float* W1 = (const float*)d_in[2];
    const float* a1s = (const float*)d_in[3];
    const float* a1d = (const float*)d_in[4];
    const float* b1 = (const float*)d_in[5];
    const float* W2 = (const float*)d_in[6];
    const float* a2s = (const float*)d_in[7];
    const float* a2d = (const float*)d_in[8];
    const float* b2 = (const float*)d_in[9];
    const float* W3 = (const float*)d_in[10];
    const float* a3s = (const float*)d_in[11];
    const float* a3d = (const float*)d_in[12];
    const float* b3 = (const float*)d_in[13];

    const int n = NN, E = EE;
    const int* src = ei;
    const int* dst = ei + E;

    char* base = (char*)d_ws;
    size_t o = 0;
    auto alloc = [&](size_t bytes) -> char* {
        char* p = base + o;
        o += (bytes + 255) & ~(size_t)255;
        return p;
    };
    int* off = (int*)alloc((n + 1) * sizeof(int));
    int* cur = (int*)alloc((n + 1) * sizeof(int));
    int* bsum = (int*)alloc(1024 * sizeof(int));
    int* es = (int*)alloc((size_t)E * sizeof(int));
    float* ssrc = (float*)alloc((size_t)n * sizeof(float));
    float* sdst = (float*)alloc((size_t)n * sizeof(float));
    float* alpha = (float*)alloc((size_t)E * sizeof(float));
    float* invden = (float*)alloc((size_t)n * sizeof(float));
    float* Hbuf = (float*)alloc((size_t)n * HH * sizeof(float));
    float* Abuf = (float*)alloc((size_t)n * HH * sizeof(float));
    (void)ws_size;

    // --- CSR build (grouped by dst) ---
    hipMemsetAsync(cur, 0, (n + 1) * sizeof(int), stream);
    hist_kernel<<<(E + 255) / 256, 256, 0, stream>>>(dst, cur, E);
    int nb = (n + SCAN_B - 1) / SCAN_B;
    scan1_kernel<<<nb, SCAN_B, 0, stream>>>(cur, off, bsum, n);
    scan2_kernel<<<1, SCAN_B, 0, stream>>>(bsum, nb);
    scan3_kernel<<<nb, SCAN_B, 0, stream>>>(off, bsum, cur, n, E);
    scatter_kernel<<<(E + 255) / 256, 256, 0, stream>>>(src, dst, cur, es, E);

    int wgrid = (n * 64 + 255) / 256;  // one wave per node

    // --- layer 1 ---
    {
        dim3 g(HH / 64, (n + 63) / 64);
        gemm_kernel<<<g, 256, 0, stream>>>(x, W1, Hbuf, n, DIN, HH);
        rowdots_kernel<<<wgrid, 256, 0, stream>>>(Hbuf, a1s, a1d, ssrc, sdst, n, HH);
        mden_kernel<<<wgrid, 256, 0, stream>>>(ssrc, sdst, off, es, alpha, invden, n);
        aggc_kernel<HH, true, false><<<n, 256, 0, stream>>>(Hbuf, alpha, invden, off, es, b1, Abuf, n);
    }
    // --- layers 2,3 (shared W2) ---
    for (int t = 0; t < 2; ++t) {
        dim3 g(HH / 64, (n + 63) / 64);
        gemm_kernel<<<g, 256, 0, stream>>>(Abuf, W2, Hbuf, n, HH, HH);
        rowdots_kernel<<<wgrid, 256, 0, stream>>>(Hbuf, a2s, a2d, ssrc, sdst, n, HH);
        mden_kernel<<<wgrid, 256, 0, stream>>>(ssrc, sdst, off, es, alpha, invden, n);
        aggc_kernel<HH, true, false><<<n, 256, 0, stream>>>(Hbuf, alpha, invden, off, es, b2, Abuf, n);
    }
    // --- layer 4: agg + feature softmax -> d_out ---
    {
        dim3 g(DOUT / 64, (n + 63) / 64);
        gemm_kernel<<<g, 256, 0, stream>>>(Abuf, W3, Hbuf, n, HH, DOUT);
        rowdots_kernel<<<wgrid, 256, 0, stream>>>(Hbuf, a3s, a3d, ssrc, sdst, n, DOUT);
        mden_kernel<<<wgrid, 256, 0, stream>>>(ssrc, sdst, off, es, alpha, invden, n);
        aggc_kernel<DOUT, false, true><<<n / 2, 256, 0, stream>>>(Hbuf, alpha, invden, off, es, b3, (float*)d_out, n);
    }
}

// Round 3
// 1262.123 us; speedup vs baseline: 1.0798x; 1.0798x over previous
//
#include <hip/hip_runtime.h>
#include <hip/hip_bf16.h>

#define NN 50000
#define EE 1600000
#define DIN 128
#define HH 256
#define DOUT 128

// ---------------- CSR build ----------------

__global__ __launch_bounds__(256) void hist_kernel(const int* __restrict__ dst, int* __restrict__ deg, int E) {
    int e = blockIdx.x * 256 + threadIdx.x;
    if (e < E) atomicAdd(&deg[dst[e]], 1);
}

#define SCAN_B 256

__global__ __launch_bounds__(SCAN_B) void scan1_kernel(const int* __restrict__ deg, int* __restrict__ exc,
                                                       int* __restrict__ bsum, int n) {
    __shared__ int tmp[SCAN_B];
    int i = blockIdx.x * SCAN_B + threadIdx.x;
    int v = (i < n) ? deg[i] : 0;
    tmp[threadIdx.x] = v;
    __syncthreads();
    for (int o = 1; o < SCAN_B; o <<= 1) {
        int t = (threadIdx.x >= o) ? tmp[threadIdx.x - o] : 0;
        __syncthreads();
        tmp[threadIdx.x] += t;
        __syncthreads();
    }
    if (i < n) exc[i] = tmp[threadIdx.x] - v;
    if (threadIdx.x == SCAN_B - 1) bsum[blockIdx.x] = tmp[SCAN_B - 1];
}

__global__ __launch_bounds__(SCAN_B) void scan2_kernel(int* __restrict__ bsum, int nb) {
    __shared__ int tmp[SCAN_B];
    int v = (threadIdx.x < nb) ? bsum[threadIdx.x] : 0;
    tmp[threadIdx.x] = v;
    __syncthreads();
    for (int o = 1; o < SCAN_B; o <<= 1) {
        int t = (threadIdx.x >= o) ? tmp[threadIdx.x - o] : 0;
        __syncthreads();
        tmp[threadIdx.x] += t;
        __syncthreads();
    }
    if (threadIdx.x < nb) bsum[threadIdx.x] = tmp[threadIdx.x] - v;
}

__global__ __launch_bounds__(SCAN_B) void scan3_kernel(int* __restrict__ exc, const int* __restrict__ bsum,
                                                       int* __restrict__ cursor, int n, int E) {
    int i = blockIdx.x * SCAN_B + threadIdx.x;
    if (i < n) {
        int v = exc[i] + bsum[blockIdx.x];
        exc[i] = v;
        cursor[i] = v;
    }
    if (i == n) exc[n] = E;
}

__global__ __launch_bounds__(256) void scatter_kernel(const int* __restrict__ src, const int* __restrict__ dst,
                                                      int* __restrict__ cursor, int* __restrict__ es, int E) {
    int e = blockIdx.x * 256 + threadIdx.x;
    if (e < E) {
        int d = dst[e];
        int pos = atomicAdd(&cursor[d], 1);
        es[pos] = src[e];
    }
}

// ---------------- fp32 GEMM 128x128x32, 8x8 register blocking, optional bias+relu ----------------

template <bool BRELU>
__global__ __launch_bounds__(256) void gemm128_kernel(const float* __restrict__ X, const float* __restrict__ W,
                                                      const float* __restrict__ bias, float* __restrict__ Hout,
                                                      int n, int K, int Cout) {
    const int BK = 32;
    __shared__ float As[BK][132];  // transposed A slice, stride 132 keeps 16B alignment
    __shared__ float Bs[BK][128];
    int tid = threadIdx.x;
    int row0 = blockIdx.y * 128;
    int col0 = blockIdx.x * 128;
    int tx = tid & 15, ty = tid >> 4;

    float acc[8][8];
#pragma unroll
    for (int i = 0; i < 8; ++i)
#pragma unroll
        for (int j = 0; j < 8; ++j) acc[i][j] = 0.f;

    for (int k0 = 0; k0 < K; k0 += BK) {
// A slice: 128 rows x 32 k, store transposed As[k][m]
#pragma unroll
        for (int i = 0; i < 4; ++i) {
            int f = tid + i * 256;  // 0..1023
            int m = f >> 3;         // 0..127
            int c4 = (f & 7) * 4;   // 0,4,..,28
            int r = row0 + m;
            float4 av = make_float4(0.f, 0.f, 0.f, 0.f);
            if (r < n) av = *(const float4*)(X + (size_t)r * K + k0 + c4);
            As[c4 + 0][m] = av.x;
            As[c4 + 1][m] = av.y;
            As[c4 + 2][m] = av.z;
            As[c4 + 3][m] = av.w;
        }
// B slice: 32 k x 128 cols
#pragma unroll
        for (int i = 0; i < 4; ++i) {
            int f = tid + i * 256;
            int kk = f >> 5;        // 0..31
            int n4 = (f & 31) * 4;  // 0..124
            float4 bv = *(const float4*)(W + (size_t)(k0 + kk) * Cout + col0 + n4);
            *(float4*)&Bs[kk][n4] = bv;
        }
        __syncthreads();
#pragma unroll 8
        for (int k = 0; k < BK; ++k) {
            float4 a0 = *(const float4*)&As[k][ty * 8];
            float4 a1 = *(const float4*)&As[k][ty * 8 + 4];
            float4 b0 = *(const float4*)&Bs[k][tx * 8];
            float4 b1 = *(const float4*)&Bs[k][tx * 8 + 4];
            float a[8] = {a0.x, a0.y, a0.z, a0.w, a1.x, a1.y, a1.z, a1.w};
            float b[8] = {b0.x, b0.y, b0.z, b0.w, b1.x, b1.y, b1.z, b1.w};
#pragma unroll
            for (int i2 = 0; i2 < 8; ++i2)
#pragma unroll
                for (int j2 = 0; j2 < 8; ++j2) acc[i2][j2] = fmaf(a[i2], b[j2], acc[i2][j2]);
        }
        __syncthreads();
    }
#pragma unroll
    for (int i = 0; i < 8; ++i) {
        int r = row0 + ty * 8 + i;
        if (r < n) {
            float o4[8];
#pragma unroll
            for (int j = 0; j < 8; ++j) {
                float v = acc[i][j];
                if (BRELU) {
                    v += bias[col0 + tx * 8 + j];
                    v = fmaxf(v, 0.f);
                }
                o4[j] = v;
            }
            float* op = Hout + (size_t)r * Cout + col0 + tx * 8;
            *(float4*)op = make_float4(o4[0], o4[1], o4[2], o4[3]);
            *(float4*)(op + 4) = make_float4(o4[4], o4[5], o4[6], o4[7]);
        }
    }
}

// ---------------- per-row dual dot: s1 = H@a1, s2 = H@a2 (also used to project a through W) ----------------

__global__ __launch_bounds__(256) void rowdots_kernel(const float* __restrict__ H, const float* __restrict__ a1,
                                                      const float* __restrict__ a2, float* __restrict__ s1,
                                                      float* __restrict__ s2, int n, int C) {
    int w = (blockIdx.x * 256 + threadIdx.x) >> 6;
    int lane = threadIdx.x & 63;
    if (w >= n) return;
    const float* hp = H + (size_t)w * C;
    float acc1 = 0.f, acc2 = 0.f;
    for (int c = lane; c < C; c += 64) {
        float hv = hp[c];
        acc1 = fmaf(hv, a1[c], acc1);
        acc2 = fmaf(hv, a2[c], acc2);
    }
#pragma unroll
    for (int o = 32; o; o >>= 1) {
        acc1 += __shfl_xor(acc1, o, 64);
        acc2 += __shfl_xor(acc2, o, 64);
    }
    if (lane == 0) {
        s1[w] = acc1;
        s2[w] = acc2;
    }
}

// ---------------- per-node softmax prep ----------------

__global__ __launch_bounds__(256) void mden_kernel(const float* __restrict__ ssrc, const float* __restrict__ sdst,
                                                   const int* __restrict__ off, const int* __restrict__ esrc,
                                                   float* __restrict__ alpha, float* __restrict__ invden, int n) {
    int w = (blockIdx.x * 256 + threadIdx.x) >> 6;
    int lane = threadIdx.x & 63;
    if (w >= n) return;
    int beg = off[w], end = off[w + 1];
    float sd = sdst[w];
    float m = -3e38f;
    for (int e = beg + lane; e < end; e += 64) {
        float v = ssrc[esrc[e]] + sd;
        v = (v > 0.f) ? v : 0.2f * v;
        alpha[e] = v;
        m = fmaxf(m, v);
    }
#pragma unroll
    for (int o = 32; o; o >>= 1) m = fmaxf(m, __shfl_xor(m, o, 64));
    float den = 0.f;
    for (int e = beg + lane; e < end; e += 64) {
        float p = __expf(alpha[e] - m);
        alpha[e] = p;
        den += p;
    }
#pragma unroll
    for (int o = 32; o; o >>= 1) den += __shfl_xor(den, o, 64);
    if (lane == 0) invden[w] = (den > 0.f) ? 1.f / den : 0.f;
}

// ---------------- aggregation: col-sliced, 64 cols per wave, 8-deep pipelined gather ----------------

template <int C, bool RELU, bool SOFTMAX>
__global__ __launch_bounds__(256) void aggc_kernel(const float* __restrict__ H, const float* __restrict__ alpha,
                                                   const float* __restrict__ invden, const int* __restrict__ off,
                                                   const int* __restrict__ esrc, const float* __restrict__ bias,
                                                   float* __restrict__ out, int n) {
    constexpr int WPN = C / 64;
    constexpr int NPB = 4 / WPN;
    int wid = threadIdx.x >> 6, lane = threadIdx.x & 63;
    int node = blockIdx.x * NPB + wid / WPN;
    int wv = wid % WPN;
    int col = wv * 64 + lane;
    int beg = (node < n) ? off[node] : 0;
    int end = (node < n) ? off[node + 1] : 0;

    float acc = 0.f;
    for (int base = beg; base < end; base += 64) {
        int e = base + lane;
        float pl = 0.f;
        int sl = 0;
        if (e < end) {
            pl = alpha[e];
            sl = esrc[e];
        }
        int cnt = end - base;
        if (cnt > 64) cnt = 64;
        int j0 = 0;
        for (; j0 + 8 <= cnt; j0 += 8) {
            float pj[8];
            const float* hp[8];
#pragma unroll
            for (int u = 0; u < 8; ++u) {
                pj[u] = __shfl(pl, j0 + u, 64);
                int sj = __shfl(sl, j0 + u, 64);
                hp[u] = H + (size_t)sj * C + col;
            }
            float hv[8];
#pragma unroll
            for (int u = 0; u < 8; ++u) hv[u] = *hp[u];
#pragma unroll
            for (int u = 0; u < 8; ++u) acc = fmaf(pj[u], hv[u], acc);
        }
        for (; j0 < cnt; ++j0) {
            float pj = __shfl(pl, j0, 64);
            int sj = __shfl(sl, j0, 64);
            acc = fmaf(pj, H[(size_t)sj * C + col], acc);
        }
    }

    float ov = 0.f;
    if (node < n) {
        float bb = bias ? bias[col] : 0.f;
        ov = fmaf(acc, invden[node], bb);
        if (RELU) ov = fmaxf(ov, 0.f);
    }
    if (SOFTMAX) {
        float mm = ov;
#pragma unroll
        for (int o = 32; o; o >>= 1) mm = fmaxf(mm, __shfl_xor(mm, o, 64));
        __shared__ float sred[4];
        if (lane == 0) sred[wid] = mm;
        __syncthreads();
        int bw = (wid / WPN) * WPN;
        mm = sred[bw];
#pragma unroll
        for (int u = 1; u < WPN; ++u) mm = fmaxf(mm, sred[bw + u]);
        float ex = __expf(ov - mm);
        float ss = ex;
#pragma unroll
        for (int o = 32; o; o >>= 1) ss += __shfl_xor(ss, o, 64);
        __syncthreads();
        if (lane == 0) sred[wid] = ss;
        __syncthreads();
        ss = 0.f;
#pragma unroll
        for (int u = 0; u < WPN; ++u) ss += sred[bw + u];
        ov = ex / ss;
    }
    if (node < n) out[(size_t)node * C + col] = ov;
}

// ---------------- launch ----------------

extern "C" void kernel_launch(void* const* d_in, const int* in_sizes, int n_in,
                              void* d_out, int out_size, void* d_ws, size_t ws_size,
                              hipStream_t stream) {
    const float* x = (const float*)d_in[0];
    const int* ei = (const int*)d_in[1];
    const float* W1 = (const float*)d_in[2];
    const float* a1s = (const float*)d_in[3];
    const float* a1d = (const float*)d_in[4];
    const float* b1 = (const float*)d_in[5];
    const float* W2 = (const float*)d_in[6];
    const float* a2s = (const float*)d_in[7];
    const float* a2d = (const float*)d_in[8];
    const float* b2 = (const float*)d_in[9];
    const float* W3 = (const float*)d_in[10];
    const float* a3s = (const float*)d_in[11];
    const float* a3d = (const float*)d_in[12];
    const float* b3 = (const float*)d_in[13];

    const int n = NN, E = EE;
    const int* src = ei;
    const int* dst = ei + E;

    char* base = (char*)d_ws;
    size_t o = 0;
    auto alloc = [&](size_t bytes) -> char* {
        char* p = base + o;
        o += (bytes + 255) & ~(size_t)255;
        return p;
    };
    int* off = (int*)alloc((n + 1) * sizeof(int));
    int* cur = (int*)alloc((n + 1) * sizeof(int));
    int* bsum = (int*)alloc(1024 * sizeof(int));
    int* es = (int*)alloc((size_t)E * sizeof(int));
    float* ssrc = (float*)alloc((size_t)n * sizeof(float));
    float* sdst = (float*)alloc((size_t)n * sizeof(float));
    float* alpha = (float*)alloc((size_t)E * sizeof(float));
    float* invden = (float*)alloc((size_t)n * sizeof(float));
    float* was = (float*)alloc(256 * sizeof(float));
    float* wad = (float*)alloc(256 * sizeof(float));
    float* Hbuf = (float*)alloc((size_t)n * HH * sizeof(float));
    float* Abuf = (float*)alloc((size_t)n * HH * sizeof(float));
    (void)ws_size;

    // --- CSR build (grouped by dst) ---
    hipMemsetAsync(cur, 0, (n + 1) * sizeof(int), stream);
    hist_kernel<<<(E + 255) / 256, 256, 0, stream>>>(dst, cur, E);
    int nb = (n + SCAN_B - 1) / SCAN_B;
    scan1_kernel<<<nb, SCAN_B, 0, stream>>>(cur, off, bsum, n);
    scan2_kernel<<<1, SCAN_B, 0, stream>>>(bsum, nb);
    scan3_kernel<<<nb, SCAN_B, 0, stream>>>(off, bsum, cur, n, E);
    scatter_kernel<<<(E + 255) / 256, 256, 0, stream>>>(src, dst, cur, es, E);

    int wgrid = (n * 64 + 255) / 256;

    // --- layer 1, reordered: logits via X@(W1 a); Z = A-hat X (C=128); out = relu(Z W1 + b1) ---
    {
        rowdots_kernel<<<(128 * 64 + 255) / 256, 256, 0, stream>>>(W1, a1s, a1d, was, wad, DIN, HH);
        rowdots_kernel<<<wgrid, 256, 0, stream>>>(x, was, wad, ssrc, sdst, n, DIN);
        mden_kernel<<<wgrid, 256, 0, stream>>>(ssrc, sdst, off, es, alpha, invden, n);
        aggc_kernel<DIN, false, false><<<n / 2, 256, 0, stream>>>(x, alpha, invden, off, es, nullptr, Hbuf, n);
        dim3 g(HH / 128, (n + 127) / 128);
        gemm128_kernel<true><<<g, 256, 0, stream>>>(Hbuf, W1, b1, Abuf, n, DIN, HH);
    }
    // --- layers 2,3 (shared W2) ---
    for (int t = 0; t < 2; ++t) {
        dim3 g(HH / 128, (n + 127) / 128);
        gemm128_kernel<false><<<g, 256, 0, stream>>>(Abuf, W2, nullptr, Hbuf, n, HH, HH);
        rowdots_kernel<<<wgrid, 256, 0, stream>>>(Hbuf, a2s, a2d, ssrc, sdst, n, HH);
        mden_kernel<<<wgrid, 256, 0, stream>>>(ssrc, sdst, off, es, alpha, invden, n);
        aggc_kernel<HH, true, false><<<n, 256, 0, stream>>>(Hbuf, alpha, invden, off, es, b2, Abuf, n);
    }
    // --- layer 4: gather H = A W3 (C=128), agg + feature softmax -> d_out ---
    {
        dim3 g(DOUT / 128, (n + 127) / 128);
        gemm128_kernel<false><<<g, 256, 0, stream>>>(Abuf, W3, nullptr, Hbuf, n, HH, DOUT);
        rowdots_kernel<<<wgrid, 256, 0, stream>>>(Hbuf, a3s, a3d, ssrc, sdst, n, DOUT);
        mden_kernel<<<wgrid, 256, 0, stream>>>(ssrc, sdst, off, es, alpha, invden, n);
        aggc_kernel<DOUT, false, true><<<n / 2, 256, 0, stream>>>(Hbuf, alpha, invden, off, es, b3, (float*)d_out, n);
    }
}

// Round 4
// 1091.864 us; speedup vs baseline: 1.2482x; 1.1559x over previous
//
#include <hip/hip_runtime.h>
#include <hip/hip_bf16.h>

#define NN 50000
#define EE 1600000
#define DIN 128
#define HH 256
#define DOUT 128

typedef __attribute__((ext_vector_type(8))) short short8;
typedef __attribute__((ext_vector_type(4))) float f32x4;

__device__ __forceinline__ short f2bf(float v) {
    union { float f; unsigned u; } a;
    a.f = v;
    unsigned r = a.u + 0x7fffu + ((a.u >> 16) & 1u);  // RTNE
    return (short)(r >> 16);
}
__device__ __forceinline__ float bf2f(short h) {
    union { unsigned u; float f; } a;
    a.u = ((unsigned)(unsigned short)h) << 16;
    return a.f;
}

// ---------------- CSR build ----------------

__global__ __launch_bounds__(256) void hist_kernel(const int* __restrict__ dst, int* __restrict__ deg, int E) {
    int e = blockIdx.x * 256 + threadIdx.x;
    if (e < E) atomicAdd(&deg[dst[e]], 1);
}

#define SCAN_B 256

__global__ __launch_bounds__(SCAN_B) void scan1_kernel(const int* __restrict__ deg, int* __restrict__ exc,
                                                       int* __restrict__ bsum, int n) {
    __shared__ int tmp[SCAN_B];
    int i = blockIdx.x * SCAN_B + threadIdx.x;
    int v = (i < n) ? deg[i] : 0;
    tmp[threadIdx.x] = v;
    __syncthreads();
    for (int o = 1; o < SCAN_B; o <<= 1) {
        int t = (threadIdx.x >= o) ? tmp[threadIdx.x - o] : 0;
        __syncthreads();
        tmp[threadIdx.x] += t;
        __syncthreads();
    }
    if (i < n) exc[i] = tmp[threadIdx.x] - v;
    if (threadIdx.x == SCAN_B - 1) bsum[blockIdx.x] = tmp[SCAN_B - 1];
}

__global__ __launch_bounds__(SCAN_B) void scan2_kernel(int* __restrict__ bsum, int nb) {
    __shared__ int tmp[SCAN_B];
    int v = (threadIdx.x < nb) ? bsum[threadIdx.x] : 0;
    tmp[threadIdx.x] = v;
    __syncthreads();
    for (int o = 1; o < SCAN_B; o <<= 1) {
        int t = (threadIdx.x >= o) ? tmp[threadIdx.x - o] : 0;
        __syncthreads();
        tmp[threadIdx.x] += t;
        __syncthreads();
    }
    if (threadIdx.x < nb) bsum[threadIdx.x] = tmp[threadIdx.x] - v;
}

__global__ __launch_bounds__(SCAN_B) void scan3_kernel(int* __restrict__ exc, const int* __restrict__ bsum,
                                                       int* __restrict__ cursor, int n, int E) {
    int i = blockIdx.x * SCAN_B + threadIdx.x;
    if (i < n) {
        int v = exc[i] + bsum[blockIdx.x];
        exc[i] = v;
        cursor[i] = v;
    }
    if (i == n) exc[n] = E;
}

__global__ __launch_bounds__(256) void scatter_kernel(const int* __restrict__ src, const int* __restrict__ dst,
                                                      int* __restrict__ cursor, int* __restrict__ es, int E) {
    int e = blockIdx.x * 256 + threadIdx.x;
    if (e < E) {
        int d = dst[e];
        int pos = atomicAdd(&cursor[d], 1);
        es[pos] = src[e];
    }
}

// ---------------- W pre-split: W[K][C] fp32 -> WhT[C][K], WlT[C][K] bf16 hi/lo ----------------

__global__ __launch_bounds__(256) void wsplit_kernel(const float* __restrict__ W, short* __restrict__ WhT,
                                                     short* __restrict__ WlT, int K, int C) {
    int f = blockIdx.x * 256 + threadIdx.x;
    if (f >= K * C) return;
    int k = f / C, c = f % C;
    float v = W[f];
    short h = f2bf(v);
    short l = f2bf(v - bf2f(h));
    WhT[(size_t)c * K + k] = h;
    WlT[(size_t)c * K + k] = l;
}

// ---------------- split-bf16 MFMA GEMM: out = X @ W (+bias, relu); W given pre-split transposed ----------------
// 128x128 tile, BK=32, 4 waves (2x2), per-wave 64x64 via 4x4 mfma_f32_16x16x32_bf16 fragments, 3 MFMA per product.

template <bool BRELU>
__global__ __launch_bounds__(256) void gemm_mfma_kernel(const float* __restrict__ X, const short* __restrict__ BhT,
                                                        const short* __restrict__ BlT, const float* __restrict__ bias,
                                                        float* __restrict__ out, int n, int K, int Cout) {
    __shared__ short Ah[128][40], Al[128][40];  // [row][k], stride 40 (80B) -> 2-way-max bank aliasing
    __shared__ short Bh[128][40], Bl[128][40];  // [col][k]
    int tid = threadIdx.x;
    int row0 = blockIdx.y * 128, col0 = blockIdx.x * 128;
    int lane = tid & 63, wid = tid >> 6;
    int wr = (wid >> 1) * 64, wc = (wid & 1) * 64;

    f32x4 acc[4][4];
#pragma unroll
    for (int mi = 0; mi < 4; ++mi)
#pragma unroll
        for (int ni = 0; ni < 4; ++ni) acc[mi][ni] = 0.f;

    int srow = tid >> 1;       // 0..127 (A-row / B-col handled by this thread)
    int sk = (tid & 1) * 16;   // k offset 0 or 16

    for (int k0 = 0; k0 < K; k0 += 32) {
        // --- stage A: rows row0..+127, k0..k0+31, split fp32 -> (hi,lo) bf16 ---
        {
            float v[16];
            int gr = row0 + srow;
            if (gr < n) {
                const float* p = X + (size_t)gr * K + k0 + sk;
                float4 f0 = ((const float4*)p)[0];
                float4 f1 = ((const float4*)p)[1];
                float4 f2 = ((const float4*)p)[2];
                float4 f3 = ((const float4*)p)[3];
                v[0] = f0.x; v[1] = f0.y; v[2] = f0.z; v[3] = f0.w;
                v[4] = f1.x; v[5] = f1.y; v[6] = f1.z; v[7] = f1.w;
                v[8] = f2.x; v[9] = f2.y; v[10] = f2.z; v[11] = f2.w;
                v[12] = f3.x; v[13] = f3.y; v[14] = f3.z; v[15] = f3.w;
            } else {
#pragma unroll
                for (int j = 0; j < 16; ++j) v[j] = 0.f;
            }
            short8 h0, h1, l0, l1;
#pragma unroll
            for (int j = 0; j < 8; ++j) {
                short h = f2bf(v[j]);
                h0[j] = h;
                l0[j] = f2bf(v[j] - bf2f(h));
            }
#pragma unroll
            for (int j = 0; j < 8; ++j) {
                short h = f2bf(v[8 + j]);
                h1[j] = h;
                l1[j] = f2bf(v[8 + j] - bf2f(h));
            }
            *(short8*)&Ah[srow][sk] = h0;
            *(short8*)&Ah[srow][sk + 8] = h1;
            *(short8*)&Al[srow][sk] = l0;
            *(short8*)&Al[srow][sk + 8] = l1;
        }
        // --- stage B: cols col0..+127, k0..k0+31 from pre-split transposed W ---
        {
            const short* ph = BhT + (size_t)(col0 + srow) * K + k0 + sk;
            const short* pl = BlT + (size_t)(col0 + srow) * K + k0 + sk;
            short8 bh0 = ((const short8*)ph)[0];
            short8 bh1 = ((const short8*)ph)[1];
            short8 bl0 = ((const short8*)pl)[0];
            short8 bl1 = ((const short8*)pl)[1];
            *(short8*)&Bh[srow][sk] = bh0;
            *(short8*)&Bh[srow][sk + 8] = bh1;
            *(short8*)&Bl[srow][sk] = bl0;
            *(short8*)&Bl[srow][sk + 8] = bl1;
        }
        __syncthreads();

        int fr = lane & 15, kb = lane >> 4;
        short8 a_h[4], a_l[4];
#pragma unroll
        for (int mi = 0; mi < 4; ++mi) {
            a_h[mi] = *(const short8*)&Ah[wr + mi * 16 + fr][kb * 8];
            a_l[mi] = *(const short8*)&Al[wr + mi * 16 + fr][kb * 8];
        }
#pragma unroll
        for (int ni = 0; ni < 4; ++ni) {
            short8 b_h = *(const short8*)&Bh[wc + ni * 16 + fr][kb * 8];
            short8 b_l = *(const short8*)&Bl[wc + ni * 16 + fr][kb * 8];
#pragma unroll
            for (int mi = 0; mi < 4; ++mi) {
                acc[mi][ni] = __builtin_amdgcn_mfma_f32_16x16x32_bf16(a_l[mi], b_h, acc[mi][ni], 0, 0, 0);
                acc[mi][ni] = __builtin_amdgcn_mfma_f32_16x16x32_bf16(a_h[mi], b_l, acc[mi][ni], 0, 0, 0);
                acc[mi][ni] = __builtin_amdgcn_mfma_f32_16x16x32_bf16(a_h[mi], b_h, acc[mi][ni], 0, 0, 0);
            }
        }
        __syncthreads();
    }

    // epilogue: D col=lane&15, row=(lane>>4)*4+r (m89-verified)
    int dc = lane & 15, dr = (lane >> 4) * 4;
#pragma unroll
    for (int mi = 0; mi < 4; ++mi) {
#pragma unroll
        for (int r = 0; r < 4; ++r) {
            int grow = row0 + wr + mi * 16 + dr + r;
            if (grow >= n) continue;
#pragma unroll
            for (int ni = 0; ni < 4; ++ni) {
                int gcol = col0 + wc + ni * 16 + dc;
                float v = acc[mi][ni][r];
                if (BRELU) {
                    v += bias[gcol];
                    v = fmaxf(v, 0.f);
                }
                out[(size_t)grow * Cout + gcol] = v;
            }
        }
    }
}

// ---------------- per-row dual dot ----------------

__global__ __launch_bounds__(256) void rowdots_kernel(const float* __restrict__ H, const float* __restrict__ a1,
                                                      const float* __restrict__ a2, float* __restrict__ s1,
                                                      float* __restrict__ s2, int n, int C) {
    int w = (blockIdx.x * 256 + threadIdx.x) >> 6;
    int lane = threadIdx.x & 63;
    if (w >= n) return;
    const float* hp = H + (size_t)w * C;
    float acc1 = 0.f, acc2 = 0.f;
    for (int c = lane; c < C; c += 64) {
        float hv = hp[c];
        acc1 = fmaf(hv, a1[c], acc1);
        acc2 = fmaf(hv, a2[c], acc2);
    }
#pragma unroll
    for (int o = 32; o; o >>= 1) {
        acc1 += __shfl_xor(acc1, o, 64);
        acc2 += __shfl_xor(acc2, o, 64);
    }
    if (lane == 0) {
        s1[w] = acc1;
        s2[w] = acc2;
    }
}

// ---------------- per-node softmax prep ----------------

__global__ __launch_bounds__(256) void mden_kernel(const float* __restrict__ ssrc, const float* __restrict__ sdst,
                                                   const int* __restrict__ off, const int* __restrict__ esrc,
                                                   float* __restrict__ alpha, float* __restrict__ invden, int n) {
    int w = (blockIdx.x * 256 + threadIdx.x) >> 6;
    int lane = threadIdx.x & 63;
    if (w >= n) return;
    int beg = off[w], end = off[w + 1];
    float sd = sdst[w];
    float m = -3e38f;
    for (int e = beg + lane; e < end; e += 64) {
        float v = ssrc[esrc[e]] + sd;
        v = (v > 0.f) ? v : 0.2f * v;
        alpha[e] = v;
        m = fmaxf(m, v);
    }
#pragma unroll
    for (int o = 32; o; o >>= 1) m = fmaxf(m, __shfl_xor(m, o, 64));
    float den = 0.f;
    for (int e = beg + lane; e < end; e += 64) {
        float p = __expf(alpha[e] - m);
        alpha[e] = p;
        den += p;
    }
#pragma unroll
    for (int o = 32; o; o >>= 1) den += __shfl_xor(den, o, 64);
    if (lane == 0) invden[w] = (den > 0.f) ? 1.f / den : 0.f;
}

// ---------------- aggregation: col-sliced gather ----------------

template <int C, bool RELU, bool SOFTMAX>
__global__ __launch_bounds__(256) void aggc_kernel(const float* __restrict__ H, const float* __restrict__ alpha,
                                                   const float* __restrict__ invden, const int* __restrict__ off,
                                                   const int* __restrict__ esrc, const float* __restrict__ bias,
                                                   float* __restrict__ out, int n) {
    constexpr int WPN = C / 64;
    constexpr int NPB = 4 / WPN;
    int wid = threadIdx.x >> 6, lane = threadIdx.x & 63;
    int node = blockIdx.x * NPB + wid / WPN;
    int wv = wid % WPN;
    int col = wv * 64 + lane;
    int beg = (node < n) ? off[node] : 0;
    int end = (node < n) ? off[node + 1] : 0;

    float acc = 0.f;
    for (int base = beg; base < end; base += 64) {
        int e = base + lane;
        float pl = 0.f;
        int sl = 0;
        if (e < end) {
            pl = alpha[e];
            sl = esrc[e];
        }
        int cnt = end - base;
        if (cnt > 64) cnt = 64;
        int j0 = 0;
        for (; j0 + 8 <= cnt; j0 += 8) {
            float pj[8];
            const float* hp[8];
#pragma unroll
            for (int u = 0; u < 8; ++u) {
                pj[u] = __shfl(pl, j0 + u, 64);
                int sj = __shfl(sl, j0 + u, 64);
                hp[u] = H + (size_t)sj * C + col;
            }
            float hv[8];
#pragma unroll
            for (int u = 0; u < 8; ++u) hv[u] = *hp[u];
#pragma unroll
            for (int u = 0; u < 8; ++u) acc = fmaf(pj[u], hv[u], acc);
        }
        for (; j0 < cnt; ++j0) {
            float pj = __shfl(pl, j0, 64);
            int sj = __shfl(sl, j0, 64);
            acc = fmaf(pj, H[(size_t)sj * C + col], acc);
        }
    }

    float ov = 0.f;
    if (node < n) {
        float bb = bias ? bias[col] : 0.f;
        ov = fmaf(acc, invden[node], bb);
        if (RELU) ov = fmaxf(ov, 0.f);
    }
    if (SOFTMAX) {
        float mm = ov;
#pragma unroll
        for (int o = 32; o; o >>= 1) mm = fmaxf(mm, __shfl_xor(mm, o, 64));
        __shared__ float sred[4];
        if (lane == 0) sred[wid] = mm;
        __syncthreads();
        int bw = (wid / WPN) * WPN;
        mm = sred[bw];
#pragma unroll
        for (int u = 1; u < WPN; ++u) mm = fmaxf(mm, sred[bw + u]);
        float ex = __expf(ov - mm);
        float ss = ex;
#pragma unroll
        for (int o = 32; o; o >>= 1) ss += __shfl_xor(ss, o, 64);
        __syncthreads();
        if (lane == 0) sred[wid] = ss;
        __syncthreads();
        ss = 0.f;
#pragma unroll
        for (int u = 0; u < WPN; ++u) ss += sred[bw + u];
        ov = ex / ss;
    }
    if (node < n) out[(size_t)node * C + col] = ov;
}

// ---------------- launch ----------------

extern "C" void kernel_launch(void* const* d_in, const int* in_sizes, int n_in,
                              void* d_out, int out_size, void* d_ws, size_t ws_size,
                              hipStream_t stream) {
    const float* x = (const float*)d_in[0];
    const int* ei = (const int*)d_in[1];
    const float* W1 = (const float*)d_in[2];
    const float* a1s = (const float*)d_in[3];
    const float* a1d = (const float*)d_in[4];
    const float* b1 = (const float*)d_in[5];
    const float* W2 = (const float*)d_in[6];
    const float* a2s = (const float*)d_in[7];
    const float* a2d = (const float*)d_in[8];
    const float* b2 = (const float*)d_in[9];
    const float* W3 = (const float*)d_in[10];
    const float* a3s = (const float*)d_in[11];
    const float* a3d = (const float*)d_in[12];
    const float* b3 = (const float*)d_in[13];

    const int n = NN, E = EE;
    const int* src = ei;
    const int* dst = ei + E;

    char* base = (char*)d_ws;
    size_t o = 0;
    auto alloc = [&](size_t bytes) -> char* {
        char* p = base + o;
        o += (bytes + 255) & ~(size_t)255;
        return p;
    };
    int* off = (int*)alloc((n + 1) * sizeof(int));
    int* cur = (int*)alloc((n + 1) * sizeof(int));
    int* bsum = (int*)alloc(1024 * sizeof(int));
    int* es = (int*)alloc((size_t)E * sizeof(int));
    float* ssrc = (float*)alloc((size_t)n * sizeof(float));
    float* sdst = (float*)alloc((size_t)n * sizeof(float));
    float* alpha = (float*)alloc((size_t)E * sizeof(float));
    float* invden = (float*)alloc((size_t)n * sizeof(float));
    float* was = (float*)alloc(256 * sizeof(float));
    float* wad = (float*)alloc(256 * sizeof(float));
    short* W1h = (short*)alloc((size_t)DIN * HH * sizeof(short));
    short* W1l = (short*)alloc((size_t)DIN * HH * sizeof(short));
    short* W2h = (short*)alloc((size_t)HH * HH * sizeof(short));
    short* W2l = (short*)alloc((size_t)HH * HH * sizeof(short));
    short* W3h = (short*)alloc((size_t)HH * DOUT * sizeof(short));
    short* W3l = (short*)alloc((size_t)HH * DOUT * sizeof(short));
    float* Hbuf = (float*)alloc((size_t)n * HH * sizeof(float));
    float* Abuf = (float*)alloc((size_t)n * HH * sizeof(float));
    (void)ws_size;

    // --- CSR build (grouped by dst) ---
    hipMemsetAsync(cur, 0, (n + 1) * sizeof(int), stream);
    hist_kernel<<<(E + 255) / 256, 256, 0, stream>>>(dst, cur, E);
    int nb = (n + SCAN_B - 1) / SCAN_B;
    scan1_kernel<<<nb, SCAN_B, 0, stream>>>(cur, off, bsum, n);
    scan2_kernel<<<1, SCAN_B, 0, stream>>>(bsum, nb);
    scan3_kernel<<<nb, SCAN_B, 0, stream>>>(off, bsum, cur, n, E);
    scatter_kernel<<<(E + 255) / 256, 256, 0, stream>>>(src, dst, cur, es, E);

    // --- W splits (once per launch) ---
    wsplit_kernel<<<(DIN * HH + 255) / 256, 256, 0, stream>>>(W1, W1h, W1l, DIN, HH);
    wsplit_kernel<<<(HH * HH + 255) / 256, 256, 0, stream>>>(W2, W2h, W2l, HH, HH);
    wsplit_kernel<<<(HH * DOUT + 255) / 256, 256, 0, stream>>>(W3, W3h, W3l, HH, DOUT);

    int wgrid = (n * 64 + 255) / 256;
    int rb = (n + 127) / 128;

    // --- layer 1, reordered: logits via X@(W1 a); Z = A-hat X (C=128); out = relu(Z W1 + b1) ---
    {
        rowdots_kernel<<<(128 * 64 + 255) / 256, 256, 0, stream>>>(W1, a1s, a1d, was, wad, DIN, HH);
        rowdots_kernel<<<wgrid, 256, 0, stream>>>(x, was, wad, ssrc, sdst, n, DIN);
        mden_kernel<<<wgrid, 256, 0, stream>>>(ssrc, sdst, off, es, alpha, invden, n);
        aggc_kernel<DIN, false, false><<<n / 2, 256, 0, stream>>>(x, alpha, invden, off, es, nullptr, Hbuf, n);
        dim3 g(HH / 128, rb);
        gemm_mfma_kernel<true><<<g, 256, 0, stream>>>(Hbuf, W1h, W1l, b1, Abuf, n, DIN, HH);
    }
    // --- layers 2,3 (shared W2) ---
    for (int t = 0; t < 2; ++t) {
        dim3 g(HH / 128, rb);
        gemm_mfma_kernel<false><<<g, 256, 0, stream>>>(Abuf, W2h, W2l, nullptr, Hbuf, n, HH, HH);
        rowdots_kernel<<<wgrid, 256, 0, stream>>>(Hbuf, a2s, a2d, ssrc, sdst, n, HH);
        mden_kernel<<<wgrid, 256, 0, stream>>>(ssrc, sdst, off, es, alpha, invden, n);
        aggc_kernel<HH, true, false><<<n, 256, 0, stream>>>(Hbuf, alpha, invden, off, es, b2, Abuf, n);
    }
    // --- layer 4: H = A W3 (C=128), agg + feature softmax -> d_out ---
    {
        dim3 g(DOUT / 128, rb);
        gemm_mfma_kernel<false><<<g, 256, 0, stream>>>(Abuf, W3h, W3l, nullptr, Hbuf, n, HH, DOUT);
        rowdots_kernel<<<wgrid, 256, 0, stream>>>(Hbuf, a3s, a3d, ssrc, sdst, n, DOUT);
        mden_kernel<<<wgrid, 256, 0, stream>>>(ssrc, sdst, off, es, alpha, invden, n);
        aggc_kernel<DOUT, false, true><<<n / 2, 256, 0, stream>>>(Hbuf, alpha, invden, off, es, b3, (float*)d_out, n);
    }
}

// Round 5
// 1063.499 us; speedup vs baseline: 1.2815x; 1.0267x over previous
//
#include <hip/hip_runtime.h>
#include <hip/hip_bf16.h>

#define NN 50000
#define EE 1600000
#define DIN 128
#define HH 256
#define DOUT 128

typedef __attribute__((ext_vector_type(8))) short short8;
typedef __attribute__((ext_vector_type(4))) float f32x4;

__device__ __forceinline__ short f2bf(float v) {
    union { float f; unsigned u; } a;
    a.f = v;
    unsigned r = a.u + 0x7fffu + ((a.u >> 16) & 1u);  // RTNE
    return (short)(r >> 16);
}
__device__ __forceinline__ float bf2f(short h) {
    union { unsigned u; float f; } a;
    a.u = ((unsigned)(unsigned short)h) << 16;
    return a.f;
}

// ---------------- CSR build ----------------

__global__ __launch_bounds__(256) void hist_kernel(const int* __restrict__ dst, int* __restrict__ deg, int E) {
    int e = blockIdx.x * 256 + threadIdx.x;
    if (e < E) atomicAdd(&deg[dst[e]], 1);
}

#define SCAN_B 256

__global__ __launch_bounds__(SCAN_B) void scan1_kernel(const int* __restrict__ deg, int* __restrict__ exc,
                                                       int* __restrict__ bsum, int n) {
    __shared__ int tmp[SCAN_B];
    int i = blockIdx.x * SCAN_B + threadIdx.x;
    int v = (i < n) ? deg[i] : 0;
    tmp[threadIdx.x] = v;
    __syncthreads();
    for (int o = 1; o < SCAN_B; o <<= 1) {
        int t = (threadIdx.x >= o) ? tmp[threadIdx.x - o] : 0;
        __syncthreads();
        tmp[threadIdx.x] += t;
        __syncthreads();
    }
    if (i < n) exc[i] = tmp[threadIdx.x] - v;
    if (threadIdx.x == SCAN_B - 1) bsum[blockIdx.x] = tmp[SCAN_B - 1];
}

__global__ __launch_bounds__(SCAN_B) void scan2_kernel(int* __restrict__ bsum, int nb) {
    __shared__ int tmp[SCAN_B];
    int v = (threadIdx.x < nb) ? bsum[threadIdx.x] : 0;
    tmp[threadIdx.x] = v;
    __syncthreads();
    for (int o = 1; o < SCAN_B; o <<= 1) {
        int t = (threadIdx.x >= o) ? tmp[threadIdx.x - o] : 0;
        __syncthreads();
        tmp[threadIdx.x] += t;
        __syncthreads();
    }
    if (threadIdx.x < nb) bsum[threadIdx.x] = tmp[threadIdx.x] - v;
}

__global__ __launch_bounds__(SCAN_B) void scan3_kernel(int* __restrict__ exc, const int* __restrict__ bsum,
                                                       int* __restrict__ cursor, int n, int E) {
    int i = blockIdx.x * SCAN_B + threadIdx.x;
    if (i < n) {
        int v = exc[i] + bsum[blockIdx.x];
        exc[i] = v;
        cursor[i] = v;
    }
    if (i == n) exc[n] = E;
}

__global__ __launch_bounds__(256) void scatter_kernel(const int* __restrict__ src, const int* __restrict__ dst,
                                                      int* __restrict__ cursor, int* __restrict__ es, int E) {
    int e = blockIdx.x * 256 + threadIdx.x;
    if (e < E) {
        int d = dst[e];
        int pos = atomicAdd(&cursor[d], 1);
        es[pos] = src[e];
    }
}

// ---------------- W pre-split ----------------

__global__ __launch_bounds__(256) void wsplit_kernel(const float* __restrict__ W, short* __restrict__ WhT,
                                                     short* __restrict__ WlT, int K, int C) {
    int f = blockIdx.x * 256 + threadIdx.x;
    if (f >= K * C) return;
    int k = f / C, c = f % C;
    float v = W[f];
    short h = f2bf(v);
    short l = f2bf(v - bf2f(h));
    WhT[(size_t)c * K + k] = h;
    WlT[(size_t)c * K + k] = l;
}

// ---------------- split-bf16 MFMA GEMM (+fused per-row attention dots via atomics) ----------------

template <bool BRELU, bool DOTS>
__global__ __launch_bounds__(256) void gemm_mfma_kernel(const float* __restrict__ X, const short* __restrict__ BhT,
                                                        const short* __restrict__ BlT, const float* __restrict__ bias,
                                                        float* __restrict__ out, const float* __restrict__ a1v,
                                                        const float* __restrict__ a2v, float* __restrict__ s1,
                                                        float* __restrict__ s2, int n, int K, int Cout) {
    __shared__ short Ah[128][40], Al[128][40];
    __shared__ short Bh[128][40], Bl[128][40];
    int tid = threadIdx.x;
    int row0 = blockIdx.y * 128, col0 = blockIdx.x * 128;
    int lane = tid & 63, wid = tid >> 6;
    int wr = (wid >> 1) * 64, wc = (wid & 1) * 64;

    f32x4 acc[4][4];
#pragma unroll
    for (int mi = 0; mi < 4; ++mi)
#pragma unroll
        for (int ni = 0; ni < 4; ++ni) acc[mi][ni] = 0.f;

    int srow = tid >> 1;
    int sk = (tid & 1) * 16;

    for (int k0 = 0; k0 < K; k0 += 32) {
        {
            float v[16];
            int gr = row0 + srow;
            if (gr < n) {
                const float* p = X + (size_t)gr * K + k0 + sk;
                float4 f0 = ((const float4*)p)[0];
                float4 f1 = ((const float4*)p)[1];
                float4 f2 = ((const float4*)p)[2];
                float4 f3 = ((const float4*)p)[3];
                v[0] = f0.x; v[1] = f0.y; v[2] = f0.z; v[3] = f0.w;
                v[4] = f1.x; v[5] = f1.y; v[6] = f1.z; v[7] = f1.w;
                v[8] = f2.x; v[9] = f2.y; v[10] = f2.z; v[11] = f2.w;
                v[12] = f3.x; v[13] = f3.y; v[14] = f3.z; v[15] = f3.w;
            } else {
#pragma unroll
                for (int j = 0; j < 16; ++j) v[j] = 0.f;
            }
            short8 h0, h1, l0, l1;
#pragma unroll
            for (int j = 0; j < 8; ++j) {
                short h = f2bf(v[j]);
                h0[j] = h;
                l0[j] = f2bf(v[j] - bf2f(h));
            }
#pragma unroll
            for (int j = 0; j < 8; ++j) {
                short h = f2bf(v[8 + j]);
                h1[j] = h;
                l1[j] = f2bf(v[8 + j] - bf2f(h));
            }
            *(short8*)&Ah[srow][sk] = h0;
            *(short8*)&Ah[srow][sk + 8] = h1;
            *(short8*)&Al[srow][sk] = l0;
            *(short8*)&Al[srow][sk + 8] = l1;
        }
        {
            const short* ph = BhT + (size_t)(col0 + srow) * K + k0 + sk;
            const short* pl = BlT + (size_t)(col0 + srow) * K + k0 + sk;
            short8 bh0 = ((const short8*)ph)[0];
            short8 bh1 = ((const short8*)ph)[1];
            short8 bl0 = ((const short8*)pl)[0];
            short8 bl1 = ((const short8*)pl)[1];
            *(short8*)&Bh[srow][sk] = bh0;
            *(short8*)&Bh[srow][sk + 8] = bh1;
            *(short8*)&Bl[srow][sk] = bl0;
            *(short8*)&Bl[srow][sk + 8] = bl1;
        }
        __syncthreads();

        int fr = lane & 15, kb = lane >> 4;
        short8 a_h[4], a_l[4];
#pragma unroll
        for (int mi = 0; mi < 4; ++mi) {
            a_h[mi] = *(const short8*)&Ah[wr + mi * 16 + fr][kb * 8];
            a_l[mi] = *(const short8*)&Al[wr + mi * 16 + fr][kb * 8];
        }
#pragma unroll
        for (int ni = 0; ni < 4; ++ni) {
            short8 b_h = *(const short8*)&Bh[wc + ni * 16 + fr][kb * 8];
            short8 b_l = *(const short8*)&Bl[wc + ni * 16 + fr][kb * 8];
#pragma unroll
            for (int mi = 0; mi < 4; ++mi) {
                acc[mi][ni] = __builtin_amdgcn_mfma_f32_16x16x32_bf16(a_l[mi], b_h, acc[mi][ni], 0, 0, 0);
                acc[mi][ni] = __builtin_amdgcn_mfma_f32_16x16x32_bf16(a_h[mi], b_l, acc[mi][ni], 0, 0, 0);
                acc[mi][ni] = __builtin_amdgcn_mfma_f32_16x16x32_bf16(a_h[mi], b_h, acc[mi][ni], 0, 0, 0);
            }
        }
        __syncthreads();
    }

    int dc = lane & 15, dr = (lane >> 4) * 4;

    if (DOTS) {
        // per-row attention logit dots (on raw pre-bias h), 16-lane reduce + atomic accumulate
#pragma unroll
        for (int mi = 0; mi < 4; ++mi) {
#pragma unroll
            for (int r = 0; r < 4; ++r) {
                float p1 = 0.f, p2 = 0.f;
#pragma unroll
                for (int ni = 0; ni < 4; ++ni) {
                    int gcol = col0 + wc + ni * 16 + dc;
                    float v = acc[mi][ni][r];
                    p1 = fmaf(v, a1v[gcol], p1);
                    p2 = fmaf(v, a2v[gcol], p2);
                }
#pragma unroll
                for (int o = 8; o; o >>= 1) {
                    p1 += __shfl_xor(p1, o, 64);
                    p2 += __shfl_xor(p2, o, 64);
                }
                int grow = row0 + wr + mi * 16 + dr + r;
                if (dc == 0 && grow < n) {
                    atomicAdd(s1 + grow, p1);
                    atomicAdd(s2 + grow, p2);
                }
            }
        }
    }

#pragma unroll
    for (int mi = 0; mi < 4; ++mi) {
#pragma unroll
        for (int r = 0; r < 4; ++r) {
            int grow = row0 + wr + mi * 16 + dr + r;
            if (grow >= n) continue;
#pragma unroll
            for (int ni = 0; ni < 4; ++ni) {
                int gcol = col0 + wc + ni * 16 + dc;
                float v = acc[mi][ni][r];
                if (BRELU) {
                    v += bias[gcol];
                    v = fmaxf(v, 0.f);
                }
                out[(size_t)grow * Cout + gcol] = v;
            }
        }
    }
}

// ---------------- per-row dual dot (layer-1 only) ----------------

__global__ __launch_bounds__(256) void rowdots_kernel(const float* __restrict__ H, const float* __restrict__ a1,
                                                      const float* __restrict__ a2, float* __restrict__ s1,
                                                      float* __restrict__ s2, int n, int C) {
    int w = (blockIdx.x * 256 + threadIdx.x) >> 6;
    int lane = threadIdx.x & 63;
    if (w >= n) return;
    const float* hp = H + (size_t)w * C;
    float acc1 = 0.f, acc2 = 0.f;
    for (int c = lane; c < C; c += 64) {
        float hv = hp[c];
        acc1 = fmaf(hv, a1[c], acc1);
        acc2 = fmaf(hv, a2[c], acc2);
    }
#pragma unroll
    for (int o = 32; o; o >>= 1) {
        acc1 += __shfl_xor(acc1, o, 64);
        acc2 += __shfl_xor(acc2, o, 64);
    }
    if (lane == 0) {
        s1[w] = acc1;
        s2[w] = acc2;
    }
}

// ---------------- per-node softmax prep ----------------

__global__ __launch_bounds__(256) void mden_kernel(const float* __restrict__ ssrc, const float* __restrict__ sdst,
                                                   const int* __restrict__ off, const int* __restrict__ esrc,
                                                   float* __restrict__ alpha, float* __restrict__ invden, int n) {
    int w = (blockIdx.x * 256 + threadIdx.x) >> 6;
    int lane = threadIdx.x & 63;
    if (w >= n) return;
    int beg = off[w], end = off[w + 1];
    float sd = sdst[w];
    float m = -3e38f;
    for (int e = beg + lane; e < end; e += 64) {
        float v = ssrc[esrc[e]] + sd;
        v = (v > 0.f) ? v : 0.2f * v;
        alpha[e] = v;
        m = fmaxf(m, v);
    }
#pragma unroll
    for (int o = 32; o; o >>= 1) m = fmaxf(m, __shfl_xor(m, o, 64));
    float den = 0.f;
    for (int e = beg + lane; e < end; e += 64) {
        float p = __expf(alpha[e] - m);
        alpha[e] = p;
        den += p;
    }
#pragma unroll
    for (int o = 32; o; o >>= 1) den += __shfl_xor(den, o, 64);
    if (lane == 0) invden[w] = (den > 0.f) ? 1.f / den : 0.f;
}

// ---------------- aggregation: col-sliced gather, CW cols per pass, row stride STRIDE ----------------

template <int CW, int STRIDE, bool RELU, bool SOFTMAX>
__global__ __launch_bounds__(256) void aggc_kernel(const float* __restrict__ H, const float* __restrict__ alpha,
                                                   const float* __restrict__ invden, const int* __restrict__ off,
                                                   const int* __restrict__ esrc, const float* __restrict__ bias,
                                                   float* __restrict__ out, int n, int colbase) {
    constexpr int WPN = CW / 64;
    constexpr int NPB = 4 / WPN;
    int wid = threadIdx.x >> 6, lane = threadIdx.x & 63;
    int node = blockIdx.x * NPB + wid / WPN;
    int wv = wid % WPN;
    int col = colbase + wv * 64 + lane;
    int beg = (node < n) ? off[node] : 0;
    int end = (node < n) ? off[node + 1] : 0;

    float acc = 0.f;
    for (int base = beg; base < end; base += 64) {
        int e = base + lane;
        float pl = 0.f;
        int sl = 0;
        if (e < end) {
            pl = alpha[e];
            sl = esrc[e];
        }
        int cnt = end - base;
        if (cnt > 64) cnt = 64;
        int j0 = 0;
        for (; j0 + 8 <= cnt; j0 += 8) {
            float pj[8];
            const float* hp[8];
#pragma unroll
            for (int u = 0; u < 8; ++u) {
                pj[u] = __shfl(pl, j0 + u, 64);
                int sj = __shfl(sl, j0 + u, 64);
                hp[u] = H + (size_t)sj * STRIDE + col;
            }
            float hv[8];
#pragma unroll
            for (int u = 0; u < 8; ++u) hv[u] = *hp[u];
#pragma unroll
            for (int u = 0; u < 8; ++u) acc = fmaf(pj[u], hv[u], acc);
        }
        for (; j0 < cnt; ++j0) {
            float pj = __shfl(pl, j0, 64);
            int sj = __shfl(sl, j0, 64);
            acc = fmaf(pj, H[(size_t)sj * STRIDE + col], acc);
        }
    }

    float ov = 0.f;
    if (node < n) {
        float bb = bias ? bias[col] : 0.f;
        ov = fmaf(acc, invden[node], bb);
        if (RELU) ov = fmaxf(ov, 0.f);
    }
    if (SOFTMAX) {
        float mm = ov;
#pragma unroll
        for (int o = 32; o; o >>= 1) mm = fmaxf(mm, __shfl_xor(mm, o, 64));
        __shared__ float sred[4];
        if (lane == 0) sred[wid] = mm;
        __syncthreads();
        int bw = (wid / WPN) * WPN;
        mm = sred[bw];
#pragma unroll
        for (int u = 1; u < WPN; ++u) mm = fmaxf(mm, sred[bw + u]);
        float ex = __expf(ov - mm);
        float ss = ex;
#pragma unroll
        for (int o = 32; o; o >>= 1) ss += __shfl_xor(ss, o, 64);
        __syncthreads();
        if (lane == 0) sred[wid] = ss;
        __syncthreads();
        ss = 0.f;
#pragma unroll
        for (int u = 0; u < WPN; ++u) ss += sred[bw + u];
        ov = ex / ss;
    }
    if (node < n) out[(size_t)node * STRIDE + col] = ov;
}

// ---------------- launch ----------------

extern "C" void kernel_launch(void* const* d_in, const int* in_sizes, int n_in,
                              void* d_out, int out_size, void* d_ws, size_t ws_size,
                              hipStream_t stream) {
    const float* x = (const float*)d_in[0];
    const int* ei = (const int*)d_in[1];
    const float* W1 = (const float*)d_in[2];
    const float* a1s = (const float*)d_in[3];
    const float* a1d = (const float*)d_in[4];
    const float* b1 = (const float*)d_in[5];
    const float* W2 = (const float*)d_in[6];
    const float* a2s = (const float*)d_in[7];
    const float* a2d = (const float*)d_in[8];
    const float* b2 = (const float*)d_in[9];
    const float* W3 = (const float*)d_in[10];
    const float* a3s = (const float*)d_in[11];
    const float* a3d = (const float*)d_in[12];
    const float* b3 = (const float*)d_in[13];

    const int n = NN, E = EE;
    const int* src = ei;
    const int* dst = ei + E;

    char* base = (char*)d_ws;
    size_t o = 0;
    auto alloc = [&](size_t bytes) -> char* {
        char* p = base + o;
        o += (bytes + 255) & ~(size_t)255;
        return p;
    };
    int* off = (int*)alloc((n + 1) * sizeof(int));
    int* cur = (int*)alloc((n + 1) * sizeof(int));
    int* bsum = (int*)alloc(1024 * sizeof(int));
    int* es = (int*)alloc((size_t)E * sizeof(int));
    float* sbuf = (float*)alloc((size_t)2 * n * sizeof(float));  // ssrc | sdst
    float* ssrc = sbuf;
    float* sdst = sbuf + n;
    float* alpha = (float*)alloc((size_t)E * sizeof(float));
    float* invden = (float*)alloc((size_t)n * sizeof(float));
    float* was = (float*)alloc(256 * sizeof(float));
    float* wad = (float*)alloc(256 * sizeof(float));
    short* W1h = (short*)alloc((size_t)DIN * HH * sizeof(short));
    short* W1l = (short*)alloc((size_t)DIN * HH * sizeof(short));
    short* W2h = (short*)alloc((size_t)HH * HH * sizeof(short));
    short* W2l = (short*)alloc((size_t)HH * HH * sizeof(short));
    short* W3h = (short*)alloc((size_t)HH * DOUT * sizeof(short));
    short* W3l = (short*)alloc((size_t)HH * DOUT * sizeof(short));
    float* Hbuf = (float*)alloc((size_t)n * HH * sizeof(float));
    float* Abuf = (float*)alloc((size_t)n * HH * sizeof(float));
    (void)ws_size;

    // --- CSR build (grouped by dst) ---
    hipMemsetAsync(cur, 0, (n + 1) * sizeof(int), stream);
    hist_kernel<<<(E + 255) / 256, 256, 0, stream>>>(dst, cur, E);
    int nb = (n + SCAN_B - 1) / SCAN_B;
    scan1_kernel<<<nb, SCAN_B, 0, stream>>>(cur, off, bsum, n);
    scan2_kernel<<<1, SCAN_B, 0, stream>>>(bsum, nb);
    scan3_kernel<<<nb, SCAN_B, 0, stream>>>(off, bsum, cur, n, E);
    scatter_kernel<<<(E + 255) / 256, 256, 0, stream>>>(src, dst, cur, es, E);

    // --- W splits ---
    wsplit_kernel<<<(DIN * HH + 255) / 256, 256, 0, stream>>>(W1, W1h, W1l, DIN, HH);
    wsplit_kernel<<<(HH * HH + 255) / 256, 256, 0, stream>>>(W2, W2h, W2l, HH, HH);
    wsplit_kernel<<<(HH * DOUT + 255) / 256, 256, 0, stream>>>(W3, W3h, W3l, HH, DOUT);

    int wgrid = (n * 64 + 255) / 256;
    int rb = (n + 127) / 128;

    // --- layer 1, reordered: logits via X@(W1 a); Z = A-hat X (C=128); A1 = relu(Z W1 + b1) ---
    {
        rowdots_kernel<<<(128 * 64 + 255) / 256, 256, 0, stream>>>(W1, a1s, a1d, was, wad, DIN, HH);
        rowdots_kernel<<<wgrid, 256, 0, stream>>>(x, was, wad, ssrc, sdst, n, DIN);
        mden_kernel<<<wgrid, 256, 0, stream>>>(ssrc, sdst, off, es, alpha, invden, n);
        aggc_kernel<DIN, DIN, false, false><<<n / 2, 256, 0, stream>>>(x, alpha, invden, off, es, nullptr, Hbuf, n, 0);
        dim3 g(HH / 128, rb);
        gemm_mfma_kernel<true, false><<<g, 256, 0, stream>>>(Hbuf, W1h, W1l, b1, Abuf, nullptr, nullptr, nullptr,
                                                             nullptr, n, DIN, HH);
    }
    // --- layer 2: gemm(+dots fused), mden, SPLIT-gather (A/B experiment arm) ---
    {
        dim3 g(HH / 128, rb);
        hipMemsetAsync(sbuf, 0, (size_t)2 * n * sizeof(float), stream);
        gemm_mfma_kernel<false, true><<<g, 256, 0, stream>>>(Abuf, W2h, W2l, nullptr, Hbuf, a2s, a2d, ssrc, sdst, n,
                                                             HH, HH);
        mden_kernel<<<wgrid, 256, 0, stream>>>(ssrc, sdst, off, es, alpha, invden, n);
        aggc_kernel<128, HH, true, false><<<n / 2, 256, 0, stream>>>(Hbuf, alpha, invden, off, es, b2, Abuf, n, 0);
        aggc_kernel<128, HH, true, false><<<n / 2, 256, 0, stream>>>(Hbuf, alpha, invden, off, es, b2, Abuf, n, 128);
    }
    // --- layer 3: gemm(+dots fused), mden, WHOLE gather (control arm) ---
    {
        dim3 g(HH / 128, rb);
        hipMemsetAsync(sbuf, 0, (size_t)2 * n * sizeof(float), stream);
        gemm_mfma_kernel<false, true><<<g, 256, 0, stream>>>(Abuf, W2h, W2l, nullptr, Hbuf, a2s, a2d, ssrc, sdst, n,
                                                             HH, HH);
        mden_kernel<<<wgrid, 256, 0, stream>>>(ssrc, sdst, off, es, alpha, invden, n);
        aggc_kernel<HH, HH, true, false><<<n, 256, 0, stream>>>(Hbuf, alpha, invden, off, es, b2, Abuf, n, 0);
    }
    // --- layer 4: gemm(+dots fused), mden, gather + feature softmax -> d_out ---
    {
        dim3 g(DOUT / 128, rb);
        hipMemsetAsync(sbuf, 0, (size_t)2 * n * sizeof(float), stream);
        gemm_mfma_kernel<false, true><<<g, 256, 0, stream>>>(Abuf, W3h, W3l, nullptr, Hbuf, a3s, a3d, ssrc, sdst, n,
                                                             HH, DOUT);
        mden_kernel<<<wgrid, 256, 0, stream>>>(ssrc, sdst, off, es, alpha, invden, n);
        aggc_kernel<DOUT, DOUT, false, true><<<n / 2, 256, 0, stream>>>(Hbuf, alpha, invden, off, es, b3,
                                                                        (float*)d_out, n, 0);
    }
}

// Round 6
// 893.546 us; speedup vs baseline: 1.5252x; 1.1902x over previous
//
#include <hip/hip_runtime.h>
#include <hip/hip_bf16.h>
#include <hip/hip_fp16.h>

#define NN 50000
#define EE 1600000
#define DIN 128
#define HH 256
#define DOUT 128

typedef __attribute__((ext_vector_type(8))) short short8;
typedef __attribute__((ext_vector_type(4))) float f32x4;

__device__ __forceinline__ short f2bf(float v) {
    union { float f; unsigned u; } a;
    a.f = v;
    unsigned r = a.u + 0x7fffu + ((a.u >> 16) & 1u);  // RTNE
    return (short)(r >> 16);
}
__device__ __forceinline__ float bf2f(short h) {
    union { unsigned u; float f; } a;
    a.u = ((unsigned)(unsigned short)h) << 16;
    return a.f;
}

// ---------------- CSR build ----------------

__global__ __launch_bounds__(256) void hist_kernel(const int* __restrict__ dst, int* __restrict__ deg, int E) {
    int e = blockIdx.x * 256 + threadIdx.x;
    if (e < E) atomicAdd(&deg[dst[e]], 1);
}

#define SCAN_B 256

__global__ __launch_bounds__(SCAN_B) void scan1_kernel(const int* __restrict__ deg, int* __restrict__ exc,
                                                       int* __restrict__ bsum, int n) {
    __shared__ int tmp[SCAN_B];
    int i = blockIdx.x * SCAN_B + threadIdx.x;
    int v = (i < n) ? deg[i] : 0;
    tmp[threadIdx.x] = v;
    __syncthreads();
    for (int o = 1; o < SCAN_B; o <<= 1) {
        int t = (threadIdx.x >= o) ? tmp[threadIdx.x - o] : 0;
        __syncthreads();
        tmp[threadIdx.x] += t;
        __syncthreads();
    }
    if (i < n) exc[i] = tmp[threadIdx.x] - v;
    if (threadIdx.x == SCAN_B - 1) bsum[blockIdx.x] = tmp[SCAN_B - 1];
}

__global__ __launch_bounds__(SCAN_B) void scan2_kernel(int* __restrict__ bsum, int nb) {
    __shared__ int tmp[SCAN_B];
    int v = (threadIdx.x < nb) ? bsum[threadIdx.x] : 0;
    tmp[threadIdx.x] = v;
    __syncthreads();
    for (int o = 1; o < SCAN_B; o <<= 1) {
        int t = (threadIdx.x >= o) ? tmp[threadIdx.x - o] : 0;
        __syncthreads();
        tmp[threadIdx.x] += t;
        __syncthreads();
    }
    if (threadIdx.x < nb) bsum[threadIdx.x] = tmp[threadIdx.x] - v;
}

__global__ __launch_bounds__(SCAN_B) void scan3_kernel(int* __restrict__ exc, const int* __restrict__ bsum,
                                                       int* __restrict__ cursor, int n, int E) {
    int i = blockIdx.x * SCAN_B + threadIdx.x;
    if (i < n) {
        int v = exc[i] + bsum[blockIdx.x];
        exc[i] = v;
        cursor[i] = v;
    }
    if (i == n) exc[n] = E;
}

__global__ __launch_bounds__(256) void scatter_kernel(const int* __restrict__ src, const int* __restrict__ dst,
                                                      int* __restrict__ cursor, int* __restrict__ es, int E) {
    int e = blockIdx.x * 256 + threadIdx.x;
    if (e < E) {
        int d = dst[e];
        int pos = atomicAdd(&cursor[d], 1);
        es[pos] = src[e];
    }
}

// ---------------- W pre-split ----------------

__global__ __launch_bounds__(256) void wsplit_kernel(const float* __restrict__ W, short* __restrict__ WhT,
                                                     short* __restrict__ WlT, int K, int C) {
    int f = blockIdx.x * 256 + threadIdx.x;
    if (f >= K * C) return;
    int k = f / C, c = f % C;
    float v = W[f];
    short h = f2bf(v);
    short l = f2bf(v - bf2f(h));
    WhT[(size_t)c * K + k] = h;
    WlT[(size_t)c * K + k] = l;
}

// ---------------- fp32 -> fp16 table convert (for layer-1 X gather) ----------------

__global__ __launch_bounds__(256) void tohalf_kernel(const float* __restrict__ in, __half* __restrict__ out,
                                                     size_t cnt) {
    size_t i = (size_t)(blockIdx.x * 256 + threadIdx.x) * 4;
    if (i + 3 < cnt) {
        float4 v = *(const float4*)(in + i);
        __half h0 = __float2half(v.x), h1 = __float2half(v.y);
        __half h2 = __float2half(v.z), h3 = __float2half(v.w);
        __half2* op = (__half2*)(out + i);
        op[0] = __half2(h0, h1);
        op[1] = __half2(h2, h3);
    }
}

// ---------------- split-bf16 MFMA GEMM (+fused dots, optional fp16 output) ----------------

template <bool BRELU, bool DOTS, bool HOUT>
__global__ __launch_bounds__(256) void gemm_mfma_kernel(const float* __restrict__ X, const short* __restrict__ BhT,
                                                        const short* __restrict__ BlT, const float* __restrict__ bias,
                                                        float* __restrict__ out, const float* __restrict__ a1v,
                                                        const float* __restrict__ a2v, float* __restrict__ s1,
                                                        float* __restrict__ s2, int n, int K, int Cout) {
    __shared__ short Ah[128][40], Al[128][40];
    __shared__ short Bh[128][40], Bl[128][40];
    int tid = threadIdx.x;
    int row0 = blockIdx.y * 128, col0 = blockIdx.x * 128;
    int lane = tid & 63, wid = tid >> 6;
    int wr = (wid >> 1) * 64, wc = (wid & 1) * 64;

    f32x4 acc[4][4];
#pragma unroll
    for (int mi = 0; mi < 4; ++mi)
#pragma unroll
        for (int ni = 0; ni < 4; ++ni) acc[mi][ni] = 0.f;

    int srow = tid >> 1;
    int sk = (tid & 1) * 16;

    for (int k0 = 0; k0 < K; k0 += 32) {
        {
            float v[16];
            int gr = row0 + srow;
            if (gr < n) {
                const float* p = X + (size_t)gr * K + k0 + sk;
                float4 f0 = ((const float4*)p)[0];
                float4 f1 = ((const float4*)p)[1];
                float4 f2 = ((const float4*)p)[2];
                float4 f3 = ((const float4*)p)[3];
                v[0] = f0.x; v[1] = f0.y; v[2] = f0.z; v[3] = f0.w;
                v[4] = f1.x; v[5] = f1.y; v[6] = f1.z; v[7] = f1.w;
                v[8] = f2.x; v[9] = f2.y; v[10] = f2.z; v[11] = f2.w;
                v[12] = f3.x; v[13] = f3.y; v[14] = f3.z; v[15] = f3.w;
            } else {
#pragma unroll
                for (int j = 0; j < 16; ++j) v[j] = 0.f;
            }
            short8 h0, h1, l0, l1;
#pragma unroll
            for (int j = 0; j < 8; ++j) {
                short h = f2bf(v[j]);
                h0[j] = h;
                l0[j] = f2bf(v[j] - bf2f(h));
            }
#pragma unroll
            for (int j = 0; j < 8; ++j) {
                short h = f2bf(v[8 + j]);
                h1[j] = h;
                l1[j] = f2bf(v[8 + j] - bf2f(h));
            }
            *(short8*)&Ah[srow][sk] = h0;
            *(short8*)&Ah[srow][sk + 8] = h1;
            *(short8*)&Al[srow][sk] = l0;
            *(short8*)&Al[srow][sk + 8] = l1;
        }
        {
            const short* ph = BhT + (size_t)(col0 + srow) * K + k0 + sk;
            const short* pl = BlT + (size_t)(col0 + srow) * K + k0 + sk;
            short8 bh0 = ((const short8*)ph)[0];
            short8 bh1 = ((const short8*)ph)[1];
            short8 bl0 = ((const short8*)pl)[0];
            short8 bl1 = ((const short8*)pl)[1];
            *(short8*)&Bh[srow][sk] = bh0;
            *(short8*)&Bh[srow][sk + 8] = bh1;
            *(short8*)&Bl[srow][sk] = bl0;
            *(short8*)&Bl[srow][sk + 8] = bl1;
        }
        __syncthreads();

        int fr = lane & 15, kb = lane >> 4;
        short8 a_h[4], a_l[4];
#pragma unroll
        for (int mi = 0; mi < 4; ++mi) {
            a_h[mi] = *(const short8*)&Ah[wr + mi * 16 + fr][kb * 8];
            a_l[mi] = *(const short8*)&Al[wr + mi * 16 + fr][kb * 8];
        }
#pragma unroll
        for (int ni = 0; ni < 4; ++ni) {
            short8 b_h = *(const short8*)&Bh[wc + ni * 16 + fr][kb * 8];
            short8 b_l = *(const short8*)&Bl[wc + ni * 16 + fr][kb * 8];
#pragma unroll
            for (int mi = 0; mi < 4; ++mi) {
                acc[mi][ni] = __builtin_amdgcn_mfma_f32_16x16x32_bf16(a_l[mi], b_h, acc[mi][ni], 0, 0, 0);
                acc[mi][ni] = __builtin_amdgcn_mfma_f32_16x16x32_bf16(a_h[mi], b_l, acc[mi][ni], 0, 0, 0);
                acc[mi][ni] = __builtin_amdgcn_mfma_f32_16x16x32_bf16(a_h[mi], b_h, acc[mi][ni], 0, 0, 0);
            }
        }
        __syncthreads();
    }

    int dc = lane & 15, dr = (lane >> 4) * 4;

    if (DOTS) {
#pragma unroll
        for (int mi = 0; mi < 4; ++mi) {
#pragma unroll
            for (int r = 0; r < 4; ++r) {
                float p1 = 0.f, p2 = 0.f;
#pragma unroll
                for (int ni = 0; ni < 4; ++ni) {
                    int gcol = col0 + wc + ni * 16 + dc;
                    float v = acc[mi][ni][r];
                    p1 = fmaf(v, a1v[gcol], p1);
                    p2 = fmaf(v, a2v[gcol], p2);
                }
#pragma unroll
                for (int o = 8; o; o >>= 1) {
                    p1 += __shfl_xor(p1, o, 64);
                    p2 += __shfl_xor(p2, o, 64);
                }
                int grow = row0 + wr + mi * 16 + dr + r;
                if (dc == 0 && grow < n) {
                    atomicAdd(s1 + grow, p1);
                    atomicAdd(s2 + grow, p2);
                }
            }
        }
    }

#pragma unroll
    for (int mi = 0; mi < 4; ++mi) {
#pragma unroll
        for (int r = 0; r < 4; ++r) {
            int grow = row0 + wr + mi * 16 + dr + r;
            if (grow >= n) continue;
#pragma unroll
            for (int ni = 0; ni < 4; ++ni) {
                int gcol = col0 + wc + ni * 16 + dc;
                float v = acc[mi][ni][r];
                if (BRELU) {
                    v += bias[gcol];
                    v = fmaxf(v, 0.f);
                }
                if (HOUT) {
                    ((__half*)out)[(size_t)grow * Cout + gcol] = __float2half(v);
                } else {
                    out[(size_t)grow * Cout + gcol] = v;
                }
            }
        }
    }
}

// ---------------- per-row dual dot (layer-1 only) ----------------

__global__ __launch_bounds__(256) void rowdots_kernel(const float* __restrict__ H, const float* __restrict__ a1,
                                                      const float* __restrict__ a2, float* __restrict__ s1,
                                                      float* __restrict__ s2, int n, int C) {
    int w = (blockIdx.x * 256 + threadIdx.x) >> 6;
    int lane = threadIdx.x & 63;
    if (w >= n) return;
    const float* hp = H + (size_t)w * C;
    float acc1 = 0.f, acc2 = 0.f;
    for (int c = lane; c < C; c += 64) {
        float hv = hp[c];
        acc1 = fmaf(hv, a1[c], acc1);
        acc2 = fmaf(hv, a2[c], acc2);
    }
#pragma unroll
    for (int o = 32; o; o >>= 1) {
        acc1 += __shfl_xor(acc1, o, 64);
        acc2 += __shfl_xor(acc2, o, 64);
    }
    if (lane == 0) {
        s1[w] = acc1;
        s2[w] = acc2;
    }
}

// ---------------- per-node softmax prep ----------------

__global__ __launch_bounds__(256) void mden_kernel(const float* __restrict__ ssrc, const float* __restrict__ sdst,
                                                   const int* __restrict__ off, const int* __restrict__ esrc,
                                                   float* __restrict__ alpha, float* __restrict__ invden, int n) {
    int w = (blockIdx.x * 256 + threadIdx.x) >> 6;
    int lane = threadIdx.x & 63;
    if (w >= n) return;
    int beg = off[w], end = off[w + 1];
    float sd = sdst[w];
    float m = -3e38f;
    for (int e = beg + lane; e < end; e += 64) {
        float v = ssrc[esrc[e]] + sd;
        v = (v > 0.f) ? v : 0.2f * v;
        alpha[e] = v;
        m = fmaxf(m, v);
    }
#pragma unroll
    for (int o = 32; o; o >>= 1) m = fmaxf(m, __shfl_xor(m, o, 64));
    float den = 0.f;
    for (int e = beg + lane; e < end; e += 64) {
        float p = __expf(alpha[e] - m);
        alpha[e] = p;
        den += p;
    }
#pragma unroll
    for (int o = 32; o; o >>= 1) den += __shfl_xor(den, o, 64);
    if (lane == 0) invden[w] = (den > 0.f) ? 1.f / den : 0.f;
}

// ---------------- aggregation: col-sliced fp16 gather ----------------

template <int CW, int STRIDE, bool RELU, bool SOFTMAX>
__global__ __launch_bounds__(256) void aggc_kernel(const __half* __restrict__ H, const float* __restrict__ alpha,
                                                   const float* __restrict__ invden, const int* __restrict__ off,
                                                   const int* __restrict__ esrc, const float* __restrict__ bias,
                                                   float* __restrict__ out, int n) {
    constexpr int WPN = CW / 64;
    constexpr int NPB = 4 / WPN;
    int wid = threadIdx.x >> 6, lane = threadIdx.x & 63;
    int node = blockIdx.x * NPB + wid / WPN;
    int wv = wid % WPN;
    int col = wv * 64 + lane;
    int beg = (node < n) ? off[node] : 0;
    int end = (node < n) ? off[node + 1] : 0;

    float acc = 0.f;
    for (int base = beg; base < end; base += 64) {
        int e = base + lane;
        float pl = 0.f;
        int sl = 0;
        if (e < end) {
            pl = alpha[e];
            sl = esrc[e];
        }
        int cnt = end - base;
        if (cnt > 64) cnt = 64;
        int j0 = 0;
        for (; j0 + 8 <= cnt; j0 += 8) {
            float pj[8];
            const __half* hp[8];
#pragma unroll
            for (int u = 0; u < 8; ++u) {
                pj[u] = __shfl(pl, j0 + u, 64);
                int sj = __shfl(sl, j0 + u, 64);
                hp[u] = H + (size_t)sj * STRIDE + col;
            }
            float hv[8];
#pragma unroll
            for (int u = 0; u < 8; ++u) hv[u] = __half2float(*hp[u]);
#pragma unroll
            for (int u = 0; u < 8; ++u) acc = fmaf(pj[u], hv[u], acc);
        }
        for (; j0 < cnt; ++j0) {
            float pj = __shfl(pl, j0, 64);
            int sj = __shfl(sl, j0, 64);
            acc = fmaf(pj, __half2float(H[(size_t)sj * STRIDE + col]), acc);
        }
    }

    float ov = 0.f;
    if (node < n) {
        float bb = bias ? bias[col] : 0.f;
        ov = fmaf(acc, invden[node], bb);
        if (RELU) ov = fmaxf(ov, 0.f);
    }
    if (SOFTMAX) {
        float mm = ov;
#pragma unroll
        for (int o = 32; o; o >>= 1) mm = fmaxf(mm, __shfl_xor(mm, o, 64));
        __shared__ float sred[4];
        if (lane == 0) sred[wid] = mm;
        __syncthreads();
        int bw = (wid / WPN) * WPN;
        mm = sred[bw];
#pragma unroll
        for (int u = 1; u < WPN; ++u) mm = fmaxf(mm, sred[bw + u]);
        float ex = __expf(ov - mm);
        float ss = ex;
#pragma unroll
        for (int o = 32; o; o >>= 1) ss += __shfl_xor(ss, o, 64);
        __syncthreads();
        if (lane == 0) sred[wid] = ss;
        __syncthreads();
        ss = 0.f;
#pragma unroll
        for (int u = 0; u < WPN; ++u) ss += sred[bw + u];
        ov = ex / ss;
    }
    if (node < n) out[(size_t)node * STRIDE + col] = ov;
}

// ---------------- launch ----------------

extern "C" void kernel_launch(void* const* d_in, const int* in_sizes, int n_in,
                              void* d_out, int out_size, void* d_ws, size_t ws_size,
                              hipStream_t stream) {
    const float* x = (const float*)d_in[0];
    const int* ei = (const int*)d_in[1];
    const float* W1 = (const float*)d_in[2];
    const float* a1s = (const float*)d_in[3];
    const float* a1d = (const float*)d_in[4];
    const float* b1 = (const float*)d_in[5];
    const float* W2 = (const float*)d_in[6];
    const float* a2s = (const float*)d_in[7];
    const float* a2d = (const float*)d_in[8];
    const float* b2 = (const float*)d_in[9];
    const float* W3 = (const float*)d_in[10];
    const float* a3s = (const float*)d_in[11];
    const float* a3d = (const float*)d_in[12];
    const float* b3 = (const float*)d_in[13];

    const int n = NN, E = EE;
    const int* src = ei;
    const int* dst = ei + E;

    char* base = (char*)d_ws;
    size_t o = 0;
    auto alloc = [&](size_t bytes) -> char* {
        char* p = base + o;
        o += (bytes + 255) & ~(size_t)255;
        return p;
    };
    int* off = (int*)alloc((n + 1) * sizeof(int));
    int* cur = (int*)alloc((n + 1) * sizeof(int));
    int* bsum = (int*)alloc(1024 * sizeof(int));
    int* es = (int*)alloc((size_t)E * sizeof(int));
    float* sbuf = (float*)alloc((size_t)2 * n * sizeof(float));  // ssrc | sdst
    float* ssrc = sbuf;
    float* sdst = sbuf + n;
    float* alpha = (float*)alloc((size_t)E * sizeof(float));
    float* invden = (float*)alloc((size_t)n * sizeof(float));
    float* was = (float*)alloc(256 * sizeof(float));
    float* wad = (float*)alloc(256 * sizeof(float));
    short* W1h = (short*)alloc((size_t)DIN * HH * sizeof(short));
    short* W1l = (short*)alloc((size_t)DIN * HH * sizeof(short));
    short* W2h = (short*)alloc((size_t)HH * HH * sizeof(short));
    short* W2l = (short*)alloc((size_t)HH * HH * sizeof(short));
    short* W3h = (short*)alloc((size_t)HH * DOUT * sizeof(short));
    short* W3l = (short*)alloc((size_t)HH * DOUT * sizeof(short));
    __half* xh = (__half*)alloc((size_t)n * DIN * sizeof(__half));
    __half* Hh = (__half*)alloc((size_t)n * HH * sizeof(__half));
    float* Hbuf = (float*)alloc((size_t)n * HH * sizeof(float));
    float* Abuf = (float*)alloc((size_t)n * HH * sizeof(float));
    (void)ws_size;

    // --- CSR build (grouped by dst) ---
    hipMemsetAsync(cur, 0, (n + 1) * sizeof(int), stream);
    hist_kernel<<<(E + 255) / 256, 256, 0, stream>>>(dst, cur, E);
    int nb = (n + SCAN_B - 1) / SCAN_B;
    scan1_kernel<<<nb, SCAN_B, 0, stream>>>(cur, off, bsum, n);
    scan2_kernel<<<1, SCAN_B, 0, stream>>>(bsum, nb);
    scan3_kernel<<<nb, SCAN_B, 0, stream>>>(off, bsum, cur, n, E);
    scatter_kernel<<<(E + 255) / 256, 256, 0, stream>>>(src, dst, cur, es, E);

    // --- W splits + X fp16 copy ---
    wsplit_kernel<<<(DIN * HH + 255) / 256, 256, 0, stream>>>(W1, W1h, W1l, DIN, HH);
    wsplit_kernel<<<(HH * HH + 255) / 256, 256, 0, stream>>>(W2, W2h, W2l, HH, HH);
    wsplit_kernel<<<(HH * DOUT + 255) / 256, 256, 0, stream>>>(W3, W3h, W3l, HH, DOUT);
    tohalf_kernel<<<((n * DIN / 4) + 255) / 256, 256, 0, stream>>>(x, xh, (size_t)n * DIN);

    int wgrid = (n * 64 + 255) / 256;
    int rb = (n + 127) / 128;

    // --- layer 1, reordered: logits via X@(W1 a); Z = A-hat X (fp16 gather, C=128); A1 = relu(Z W1 + b1) ---
    {
        rowdots_kernel<<<(128 * 64 + 255) / 256, 256, 0, stream>>>(W1, a1s, a1d, was, wad, DIN, HH);
        rowdots_kernel<<<wgrid, 256, 0, stream>>>(x, was, wad, ssrc, sdst, n, DIN);
        mden_kernel<<<wgrid, 256, 0, stream>>>(ssrc, sdst, off, es, alpha, invden, n);
        aggc_kernel<DIN, DIN, false, false><<<n / 2, 256, 0, stream>>>(xh, alpha, invden, off, es, nullptr, Hbuf, n);
        dim3 g(HH / 128, rb);
        gemm_mfma_kernel<true, false, false><<<g, 256, 0, stream>>>(Hbuf, W1h, W1l, b1, Abuf, nullptr, nullptr,
                                                                    nullptr, nullptr, n, DIN, HH);
    }
    // --- layers 2,3 (shared W2): gemm(fp16 H out + fused dots), mden, fp16 gather ---
    for (int t = 0; t < 2; ++t) {
        dim3 g(HH / 128, rb);
        hipMemsetAsync(sbuf, 0, (size_t)2 * n * sizeof(float), stream);
        gemm_mfma_kernel<false, true, true><<<g, 256, 0, stream>>>(Abuf, W2h, W2l, nullptr, (float*)Hh, a2s, a2d,
                                                                   ssrc, sdst, n, HH, HH);
        mden_kernel<<<wgrid, 256, 0, stream>>>(ssrc, sdst, off, es, alpha, invden, n);
        aggc_kernel<HH, HH, true, false><<<n, 256, 0, stream>>>(Hh, alpha, invden, off, es, b2, Abuf, n);
    }
    // --- layer 4: gemm(fp16 H out + fused dots), mden, fp16 gather + feature softmax -> d_out ---
    {
        dim3 g(DOUT / 128, rb);
        hipMemsetAsync(sbuf, 0, (size_t)2 * n * sizeof(float), stream);
        gemm_mfma_kernel<false, true, true><<<g, 256, 0, stream>>>(Abuf, W3h, W3l, nullptr, (float*)Hh, a3s, a3d,
                                                                   ssrc, sdst, n, HH, DOUT);
        mden_kernel<<<wgrid, 256, 0, stream>>>(ssrc, sdst, off, es, alpha, invden, n);
        aggc_kernel<DOUT, DOUT, false, true><<<n / 2, 256, 0, stream>>>(Hh, alpha, invden, off, es, b3,
                                                                        (float*)d_out, n);
    }
}

// Round 7
// 760.661 us; speedup vs baseline: 1.7917x; 1.1747x over previous
//
#include <hip/hip_runtime.h>
#include <hip/hip_bf16.h>
#include <hip/hip_fp16.h>

#define NN 50000
#define EE 1600000
#define DIN 128
#define HH 256
#define DOUT 128

typedef __attribute__((ext_vector_type(8))) short short8;
typedef __attribute__((ext_vector_type(4))) float f32x4;

__device__ __forceinline__ short f2bf(float v) {
    union { float f; unsigned u; } a;
    a.f = v;
    unsigned r = a.u + 0x7fffu + ((a.u >> 16) & 1u);  // RTNE
    return (short)(r >> 16);
}
__device__ __forceinline__ float bf2f(short h) {
    union { unsigned u; float f; } a;
    a.u = ((unsigned)(unsigned short)h) << 16;
    return a.f;
}

// ---------------- CSR build ----------------

__global__ __launch_bounds__(256) void hist_kernel(const int* __restrict__ dst, int* __restrict__ deg, int E) {
    int e = blockIdx.x * 256 + threadIdx.x;
    if (e < E) atomicAdd(&deg[dst[e]], 1);
}

#define SCAN_B 256

__global__ __launch_bounds__(SCAN_B) void scan1_kernel(const int* __restrict__ deg, int* __restrict__ exc,
                                                       int* __restrict__ bsum, int n) {
    __shared__ int tmp[SCAN_B];
    int i = blockIdx.x * SCAN_B + threadIdx.x;
    int v = (i < n) ? deg[i] : 0;
    tmp[threadIdx.x] = v;
    __syncthreads();
    for (int o = 1; o < SCAN_B; o <<= 1) {
        int t = (threadIdx.x >= o) ? tmp[threadIdx.x - o] : 0;
        __syncthreads();
        tmp[threadIdx.x] += t;
        __syncthreads();
    }
    if (i < n) exc[i] = tmp[threadIdx.x] - v;
    if (threadIdx.x == SCAN_B - 1) bsum[blockIdx.x] = tmp[SCAN_B - 1];
}

__global__ __launch_bounds__(SCAN_B) void scan2_kernel(int* __restrict__ bsum, int nb) {
    __shared__ int tmp[SCAN_B];
    int v = (threadIdx.x < nb) ? bsum[threadIdx.x] : 0;
    tmp[threadIdx.x] = v;
    __syncthreads();
    for (int o = 1; o < SCAN_B; o <<= 1) {
        int t = (threadIdx.x >= o) ? tmp[threadIdx.x - o] : 0;
        __syncthreads();
        tmp[threadIdx.x] += t;
        __syncthreads();
    }
    if (threadIdx.x < nb) bsum[threadIdx.x] = tmp[threadIdx.x] - v;
}

__global__ __launch_bounds__(SCAN_B) void scan3_kernel(int* __restrict__ exc, const int* __restrict__ bsum,
                                                       int* __restrict__ cursor, int n, int E) {
    int i = blockIdx.x * SCAN_B + threadIdx.x;
    if (i < n) {
        int v = exc[i] + bsum[blockIdx.x];
        exc[i] = v;
        cursor[i] = v;
    }
    if (i == n) exc[n] = E;
}

__global__ __launch_bounds__(256) void scatter_kernel(const int* __restrict__ src, const int* __restrict__ dst,
                                                      int* __restrict__ cursor, int* __restrict__ es, int E) {
    int e = blockIdx.x * 256 + threadIdx.x;
    if (e < E) {
        int d = dst[e];
        int pos = atomicAdd(&cursor[d], 1);
        es[pos] = src[e];
    }
}

// ---------------- W pre-split ----------------

__global__ __launch_bounds__(256) void wsplit_kernel(const float* __restrict__ W, short* __restrict__ WhT,
                                                     short* __restrict__ WlT, int K, int C) {
    int f = blockIdx.x * 256 + threadIdx.x;
    if (f >= K * C) return;
    int k = f / C, c = f % C;
    float v = W[f];
    short h = f2bf(v);
    short l = f2bf(v - bf2f(h));
    WhT[(size_t)c * K + k] = h;
    WlT[(size_t)c * K + k] = l;
}

// ---------------- fp32 -> fp16 table convert ----------------

__global__ __launch_bounds__(256) void tohalf_kernel(const float* __restrict__ in, __half* __restrict__ out,
                                                     size_t cnt) {
    size_t i = (size_t)(blockIdx.x * 256 + threadIdx.x) * 4;
    if (i + 3 < cnt) {
        float4 v = *(const float4*)(in + i);
        __half h0 = __float2half(v.x), h1 = __float2half(v.y);
        __half h2 = __float2half(v.z), h3 = __float2half(v.w);
        __half2* op = (__half2*)(out + i);
        op[0] = __half2(h0, h1);
        op[1] = __half2(h2, h3);
    }
}

// ---------------- split-bf16 MFMA GEMM (+fused dots, optional fp16 output) ----------------

template <bool BRELU, bool DOTS, bool HOUT>
__global__ __launch_bounds__(256) void gemm_mfma_kernel(const float* __restrict__ X, const short* __restrict__ BhT,
                                                        const short* __restrict__ BlT, const float* __restrict__ bias,
                                                        float* __restrict__ out, const float* __restrict__ a1v,
                                                        const float* __restrict__ a2v, float* __restrict__ s1,
                                                        float* __restrict__ s2, int n, int K, int Cout) {
    __shared__ short Ah[128][40], Al[128][40];
    __shared__ short Bh[128][40], Bl[128][40];
    int tid = threadIdx.x;
    int row0 = blockIdx.y * 128, col0 = blockIdx.x * 128;
    int lane = tid & 63, wid = tid >> 6;
    int wr = (wid >> 1) * 64, wc = (wid & 1) * 64;

    f32x4 acc[4][4];
#pragma unroll
    for (int mi = 0; mi < 4; ++mi)
#pragma unroll
        for (int ni = 0; ni < 4; ++ni) acc[mi][ni] = 0.f;

    int srow = tid >> 1;
    int sk = (tid & 1) * 16;

    for (int k0 = 0; k0 < K; k0 += 32) {
        {
            float v[16];
            int gr = row0 + srow;
            if (gr < n) {
                const float* p = X + (size_t)gr * K + k0 + sk;
                float4 f0 = ((const float4*)p)[0];
                float4 f1 = ((const float4*)p)[1];
                float4 f2 = ((const float4*)p)[2];
                float4 f3 = ((const float4*)p)[3];
                v[0] = f0.x; v[1] = f0.y; v[2] = f0.z; v[3] = f0.w;
                v[4] = f1.x; v[5] = f1.y; v[6] = f1.z; v[7] = f1.w;
                v[8] = f2.x; v[9] = f2.y; v[10] = f2.z; v[11] = f2.w;
                v[12] = f3.x; v[13] = f3.y; v[14] = f3.z; v[15] = f3.w;
            } else {
#pragma unroll
                for (int j = 0; j < 16; ++j) v[j] = 0.f;
            }
            short8 h0, h1, l0, l1;
#pragma unroll
            for (int j = 0; j < 8; ++j) {
                short h = f2bf(v[j]);
                h0[j] = h;
                l0[j] = f2bf(v[j] - bf2f(h));
            }
#pragma unroll
            for (int j = 0; j < 8; ++j) {
                short h = f2bf(v[8 + j]);
                h1[j] = h;
                l1[j] = f2bf(v[8 + j] - bf2f(h));
            }
            *(short8*)&Ah[srow][sk] = h0;
            *(short8*)&Ah[srow][sk + 8] = h1;
            *(short8*)&Al[srow][sk] = l0;
            *(short8*)&Al[srow][sk + 8] = l1;
        }
        {
            const short* ph = BhT + (size_t)(col0 + srow) * K + k0 + sk;
            const short* pl = BlT + (size_t)(col0 + srow) * K + k0 + sk;
            short8 bh0 = ((const short8*)ph)[0];
            short8 bh1 = ((const short8*)ph)[1];
            short8 bl0 = ((const short8*)pl)[0];
            short8 bl1 = ((const short8*)pl)[1];
            *(short8*)&Bh[srow][sk] = bh0;
            *(short8*)&Bh[srow][sk + 8] = bh1;
            *(short8*)&Bl[srow][sk] = bl0;
            *(short8*)&Bl[srow][sk + 8] = bl1;
        }
        __syncthreads();

        int fr = lane & 15, kb = lane >> 4;
        short8 a_h[4], a_l[4];
#pragma unroll
        for (int mi = 0; mi < 4; ++mi) {
            a_h[mi] = *(const short8*)&Ah[wr + mi * 16 + fr][kb * 8];
            a_l[mi] = *(const short8*)&Al[wr + mi * 16 + fr][kb * 8];
        }
#pragma unroll
        for (int ni = 0; ni < 4; ++ni) {
            short8 b_h = *(const short8*)&Bh[wc + ni * 16 + fr][kb * 8];
            short8 b_l = *(const short8*)&Bl[wc + ni * 16 + fr][kb * 8];
#pragma unroll
            for (int mi = 0; mi < 4; ++mi) {
                acc[mi][ni] = __builtin_amdgcn_mfma_f32_16x16x32_bf16(a_l[mi], b_h, acc[mi][ni], 0, 0, 0);
                acc[mi][ni] = __builtin_amdgcn_mfma_f32_16x16x32_bf16(a_h[mi], b_l, acc[mi][ni], 0, 0, 0);
                acc[mi][ni] = __builtin_amdgcn_mfma_f32_16x16x32_bf16(a_h[mi], b_h, acc[mi][ni], 0, 0, 0);
            }
        }
        __syncthreads();
    }

    int dc = lane & 15, dr = (lane >> 4) * 4;

    if (DOTS) {
#pragma unroll
        for (int mi = 0; mi < 4; ++mi) {
#pragma unroll
            for (int r = 0; r < 4; ++r) {
                float p1 = 0.f, p2 = 0.f;
#pragma unroll
                for (int ni = 0; ni < 4; ++ni) {
                    int gcol = col0 + wc + ni * 16 + dc;
                    float v = acc[mi][ni][r];
                    p1 = fmaf(v, a1v[gcol], p1);
                    p2 = fmaf(v, a2v[gcol], p2);
                }
#pragma unroll
                for (int o = 8; o; o >>= 1) {
                    p1 += __shfl_xor(p1, o, 64);
                    p2 += __shfl_xor(p2, o, 64);
                }
                int grow = row0 + wr + mi * 16 + dr + r;
                if (dc == 0 && grow < n) {
                    atomicAdd(s1 + grow, p1);
                    atomicAdd(s2 + grow, p2);
                }
            }
        }
    }

#pragma unroll
    for (int mi = 0; mi < 4; ++mi) {
#pragma unroll
        for (int r = 0; r < 4; ++r) {
            int grow = row0 + wr + mi * 16 + dr + r;
            if (grow >= n) continue;
#pragma unroll
            for (int ni = 0; ni < 4; ++ni) {
                int gcol = col0 + wc + ni * 16 + dc;
                float v = acc[mi][ni][r];
                if (BRELU) {
                    v += bias[gcol];
                    v = fmaxf(v, 0.f);
                }
                if (HOUT) {
                    ((__half*)out)[(size_t)grow * Cout + gcol] = __float2half(v);
                } else {
                    out[(size_t)grow * Cout + gcol] = v;
                }
            }
        }
    }
}

// ---------------- per-row dual dot (layer-1 only) ----------------

__global__ __launch_bounds__(256) void rowdots_kernel(const float* __restrict__ H, const float* __restrict__ a1,
                                                      const float* __restrict__ a2, float* __restrict__ s1,
                                                      float* __restrict__ s2, int n, int C) {
    int w = (blockIdx.x * 256 + threadIdx.x) >> 6;
    int lane = threadIdx.x & 63;
    if (w >= n) return;
    const float* hp = H + (size_t)w * C;
    float acc1 = 0.f, acc2 = 0.f;
    for (int c = lane; c < C; c += 64) {
        float hv = hp[c];
        acc1 = fmaf(hv, a1[c], acc1);
        acc2 = fmaf(hv, a2[c], acc2);
    }
#pragma unroll
    for (int o = 32; o; o >>= 1) {
        acc1 += __shfl_xor(acc1, o, 64);
        acc2 += __shfl_xor(acc2, o, 64);
    }
    if (lane == 0) {
        s1[w] = acc1;
        s2[w] = acc2;
    }
}

// ---------------- per-node softmax prep ----------------

__global__ __launch_bounds__(256) void mden_kernel(const float* __restrict__ ssrc, const float* __restrict__ sdst,
                                                   const int* __restrict__ off, const int* __restrict__ esrc,
                                                   float* __restrict__ alpha, float* __restrict__ invden, int n) {
    int w = (blockIdx.x * 256 + threadIdx.x) >> 6;
    int lane = threadIdx.x & 63;
    if (w >= n) return;
    int beg = off[w], end = off[w + 1];
    float sd = sdst[w];
    float m = -3e38f;
    for (int e = beg + lane; e < end; e += 64) {
        float v = ssrc[esrc[e]] + sd;
        v = (v > 0.f) ? v : 0.2f * v;
        alpha[e] = v;
        m = fmaxf(m, v);
    }
#pragma unroll
    for (int o = 32; o; o >>= 1) m = fmaxf(m, __shfl_xor(m, o, 64));
    float den = 0.f;
    for (int e = beg + lane; e < end; e += 64) {
        float p = __expf(alpha[e] - m);
        alpha[e] = p;
        den += p;
    }
#pragma unroll
    for (int o = 32; o; o >>= 1) den += __shfl_xor(den, o, 64);
    if (lane == 0) invden[w] = (den > 0.f) ? 1.f / den : 0.f;
}

// ---------------- aggregation: half2 gather, 128 cols per wave ----------------
// WPN = C/128 waves per node; each lane owns 2 adjacent cols (4B load per edge).

template <int C, bool RELU, bool SOFTMAX>
__global__ __launch_bounds__(256) void aggc2_kernel(const __half* __restrict__ H, const float* __restrict__ alpha,
                                                    const float* __restrict__ invden, const int* __restrict__ off,
                                                    const int* __restrict__ esrc, const float* __restrict__ bias,
                                                    float* __restrict__ out, int n) {
    constexpr int WPN = C / 128;  // 2 for C=256, 1 for C=128
    constexpr int NPB = 4 / WPN;
    int wid = threadIdx.x >> 6, lane = threadIdx.x & 63;
    int node = blockIdx.x * NPB + (WPN == 1 ? wid : (wid >> 1));
    int wv = (WPN == 1) ? 0 : (wid & 1);
    int c0 = wv * 128 + lane * 2;
    int beg = (node < n) ? off[node] : 0;
    int end = (node < n) ? off[node + 1] : 0;

    float acc0 = 0.f, acc1 = 0.f;
    for (int base = beg; base < end; base += 64) {
        int e = base + lane;
        float pl = 0.f;
        int sl = 0;
        if (e < end) {
            pl = alpha[e];
            sl = esrc[e];
        }
        int cnt = end - base;
        if (cnt > 64) cnt = 64;
        int j0 = 0;
        for (; j0 + 8 <= cnt; j0 += 8) {
            float pj[8];
            const __half2* hp[8];
#pragma unroll
            for (int u = 0; u < 8; ++u) {
                pj[u] = __shfl(pl, j0 + u, 64);
                int sj = __shfl(sl, j0 + u, 64);
                hp[u] = (const __half2*)(H + (size_t)sj * C + c0);
            }
            __half2 hv[8];
#pragma unroll
            for (int u = 0; u < 8; ++u) hv[u] = *hp[u];
#pragma unroll
            for (int u = 0; u < 8; ++u) {
                float2 f = __half22float2(hv[u]);
                acc0 = fmaf(pj[u], f.x, acc0);
                acc1 = fmaf(pj[u], f.y, acc1);
            }
        }
        for (; j0 < cnt; ++j0) {
            float pj = __shfl(pl, j0, 64);
            int sj = __shfl(sl, j0, 64);
            float2 f = __half22float2(*(const __half2*)(H + (size_t)sj * C + c0));
            acc0 = fmaf(pj, f.x, acc0);
            acc1 = fmaf(pj, f.y, acc1);
        }
    }

    float ov0 = 0.f, ov1 = 0.f;
    if (node < n) {
        float inv = invden[node];
        float bb0 = bias ? bias[c0] : 0.f;
        float bb1 = bias ? bias[c0 + 1] : 0.f;
        ov0 = fmaf(acc0, inv, bb0);
        ov1 = fmaf(acc1, inv, bb1);
        if (RELU) {
            ov0 = fmaxf(ov0, 0.f);
            ov1 = fmaxf(ov1, 0.f);
        }
    }
    if (SOFTMAX) {
        // C=128, WPN=1: whole row within this wave
        float mm = fmaxf(ov0, ov1);
#pragma unroll
        for (int o = 32; o; o >>= 1) mm = fmaxf(mm, __shfl_xor(mm, o, 64));
        float e0 = __expf(ov0 - mm), e1 = __expf(ov1 - mm);
        float ss = e0 + e1;
#pragma unroll
        for (int o = 32; o; o >>= 1) ss += __shfl_xor(ss, o, 64);
        float si = 1.f / ss;
        ov0 = e0 * si;
        ov1 = e1 * si;
    }
    if (node < n) *(float2*)(out + (size_t)node * C + c0) = make_float2(ov0, ov1);
}

// ---------------- launch ----------------

extern "C" void kernel_launch(void* const* d_in, const int* in_sizes, int n_in,
                              void* d_out, int out_size, void* d_ws, size_t ws_size,
                              hipStream_t stream) {
    const float* x = (const float*)d_in[0];
    const int* ei = (const int*)d_in[1];
    const float* W1 = (const float*)d_in[2];
    const float* a1s = (const float*)d_in[3];
    const float* a1d = (const float*)d_in[4];
    const float* b1 = (const float*)d_in[5];
    const float* W2 = (const float*)d_in[6];
    const float* a2s = (const float*)d_in[7];
    const float* a2d = (const float*)d_in[8];
    const float* b2 = (const float*)d_in[9];
    const float* W3 = (const float*)d_in[10];
    const float* a3s = (const float*)d_in[11];
    const float* a3d = (const float*)d_in[12];
    const float* b3 = (const float*)d_in[13];

    const int n = NN, E = EE;
    const int* src = ei;
    const int* dst = ei + E;

    char* base = (char*)d_ws;
    size_t o = 0;
    auto alloc = [&](size_t bytes) -> char* {
        char* p = base + o;
        o += (bytes + 255) & ~(size_t)255;
        return p;
    };
    int* off = (int*)alloc((n + 1) * sizeof(int));
    int* cur = (int*)alloc((n + 1) * sizeof(int));
    int* bsum = (int*)alloc(1024 * sizeof(int));
    int* es = (int*)alloc((size_t)E * sizeof(int));
    float* sbuf = (float*)alloc((size_t)2 * n * sizeof(float));  // ssrc | sdst
    float* ssrc = sbuf;
    float* sdst = sbuf + n;
    float* alpha = (float*)alloc((size_t)E * sizeof(float));
    float* invden = (float*)alloc((size_t)n * sizeof(float));
    float* was = (float*)alloc(256 * sizeof(float));
    float* wad = (float*)alloc(256 * sizeof(float));
    short* W1h = (short*)alloc((size_t)DIN * HH * sizeof(short));
    short* W1l = (short*)alloc((size_t)DIN * HH * sizeof(short));
    short* W2h = (short*)alloc((size_t)HH * HH * sizeof(short));
    short* W2l = (short*)alloc((size_t)HH * HH * sizeof(short));
    short* W3h = (short*)alloc((size_t)HH * DOUT * sizeof(short));
    short* W3l = (short*)alloc((size_t)HH * DOUT * sizeof(short));
    __half* xh = (__half*)alloc((size_t)n * DIN * sizeof(__half));
    __half* Hh = (__half*)alloc((size_t)n * HH * sizeof(__half));
    float* Hbuf = (float*)alloc((size_t)n * HH * sizeof(float));
    float* Abuf = (float*)alloc((size_t)n * HH * sizeof(float));
    (void)ws_size;

    // --- CSR build (grouped by dst) ---
    hipMemsetAsync(cur, 0, (n + 1) * sizeof(int), stream);
    hist_kernel<<<(E + 255) / 256, 256, 0, stream>>>(dst, cur, E);
    int nb = (n + SCAN_B - 1) / SCAN_B;
    scan1_kernel<<<nb, SCAN_B, 0, stream>>>(cur, off, bsum, n);
    scan2_kernel<<<1, SCAN_B, 0, stream>>>(bsum, nb);
    scan3_kernel<<<nb, SCAN_B, 0, stream>>>(off, bsum, cur, n, E);
    scatter_kernel<<<(E + 255) / 256, 256, 0, stream>>>(src, dst, cur, es, E);

    // --- W splits + X fp16 copy ---
    wsplit_kernel<<<(DIN * HH + 255) / 256, 256, 0, stream>>>(W1, W1h, W1l, DIN, HH);
    wsplit_kernel<<<(HH * HH + 255) / 256, 256, 0, stream>>>(W2, W2h, W2l, HH, HH);
    wsplit_kernel<<<(HH * DOUT + 255) / 256, 256, 0, stream>>>(W3, W3h, W3l, HH, DOUT);
    tohalf_kernel<<<((n * DIN / 4) + 255) / 256, 256, 0, stream>>>(x, xh, (size_t)n * DIN);

    int wgrid = (n * 64 + 255) / 256;
    int rb = (n + 127) / 128;

    // --- layer 1, reordered: logits via X@(W1 a); Z = A-hat X (fp16 gather, C=128); A1 = relu(Z W1 + b1) ---
    {
        rowdots_kernel<<<(128 * 64 + 255) / 256, 256, 0, stream>>>(W1, a1s, a1d, was, wad, DIN, HH);
        rowdots_kernel<<<wgrid, 256, 0, stream>>>(x, was, wad, ssrc, sdst, n, DIN);
        mden_kernel<<<wgrid, 256, 0, stream>>>(ssrc, sdst, off, es, alpha, invden, n);
        aggc2_kernel<DIN, false, false><<<n / 4, 256, 0, stream>>>(xh, alpha, invden, off, es, nullptr, Hbuf, n);
        dim3 g(HH / 128, rb);
        gemm_mfma_kernel<true, false, false><<<g, 256, 0, stream>>>(Hbuf, W1h, W1l, b1, Abuf, nullptr, nullptr,
                                                                    nullptr, nullptr, n, DIN, HH);
    }
    // --- layers 2,3 (shared W2): gemm(fp16 H out + fused dots), mden, half2 gather ---
    for (int t = 0; t < 2; ++t) {
        dim3 g(HH / 128, rb);
        hipMemsetAsync(sbuf, 0, (size_t)2 * n * sizeof(float), stream);
        gemm_mfma_kernel<false, true, true><<<g, 256, 0, stream>>>(Abuf, W2h, W2l, nullptr, (float*)Hh, a2s, a2d,
                                                                   ssrc, sdst, n, HH, HH);
        mden_kernel<<<wgrid, 256, 0, stream>>>(ssrc, sdst, off, es, alpha, invden, n);
        aggc2_kernel<HH, true, false><<<n / 2, 256, 0, stream>>>(Hh, alpha, invden, off, es, b2, Abuf, n);
    }
    // --- layer 4: gemm(fp16 H out + fused dots), mden, half2 gather + in-wave feature softmax -> d_out ---
    {
        dim3 g(DOUT / 128, rb);
        hipMemsetAsync(sbuf, 0, (size_t)2 * n * sizeof(float), stream);
        gemm_mfma_kernel<false, true, true><<<g, 256, 0, stream>>>(Abuf, W3h, W3l, nullptr, (float*)Hh, a3s, a3d,
                                                                   ssrc, sdst, n, HH, DOUT);
        mden_kernel<<<wgrid, 256, 0, stream>>>(ssrc, sdst, off, es, alpha, invden, n);
        aggc2_kernel<DOUT, false, true><<<n / 4, 256, 0, stream>>>(Hh, alpha, invden, off, es, b3, (float*)d_out, n);
    }
}

// Round 8
// 665.543 us; speedup vs baseline: 2.0477x; 1.1429x over previous
//
#include <hip/hip_runtime.h>
#include <hip/hip_bf16.h>
#include <hip/hip_fp16.h>

#define NN 50000
#define EE 1600000
#define DIN 128
#define HH 256
#define DOUT 128

typedef __attribute__((ext_vector_type(8))) short short8;
typedef __attribute__((ext_vector_type(4))) float f32x4;

__device__ __forceinline__ short f2bf(float v) {
    union { float f; unsigned u; } a;
    a.f = v;
    unsigned r = a.u + 0x7fffu + ((a.u >> 16) & 1u);  // RTNE
    return (short)(r >> 16);
}
__device__ __forceinline__ float bf2f(short h) {
    union { unsigned u; float f; } a;
    a.u = ((unsigned)(unsigned short)h) << 16;
    return a.f;
}

// ---------------- CSR build ----------------

__global__ __launch_bounds__(256) void hist_kernel(const int* __restrict__ dst, int* __restrict__ deg, int E) {
    int e = blockIdx.x * 256 + threadIdx.x;
    if (e < E) atomicAdd(&deg[dst[e]], 1);
}

#define SCAN_B 256

__global__ __launch_bounds__(SCAN_B) void scan1_kernel(const int* __restrict__ deg, int* __restrict__ exc,
                                                       int* __restrict__ bsum, int n) {
    __shared__ int tmp[SCAN_B];
    int i = blockIdx.x * SCAN_B + threadIdx.x;
    int v = (i < n) ? deg[i] : 0;
    tmp[threadIdx.x] = v;
    __syncthreads();
    for (int o = 1; o < SCAN_B; o <<= 1) {
        int t = (threadIdx.x >= o) ? tmp[threadIdx.x - o] : 0;
        __syncthreads();
        tmp[threadIdx.x] += t;
        __syncthreads();
    }
    if (i < n) exc[i] = tmp[threadIdx.x] - v;
    if (threadIdx.x == SCAN_B - 1) bsum[blockIdx.x] = tmp[SCAN_B - 1];
}

__global__ __launch_bounds__(SCAN_B) void scan2_kernel(int* __restrict__ bsum, int nb) {
    __shared__ int tmp[SCAN_B];
    int v = (threadIdx.x < nb) ? bsum[threadIdx.x] : 0;
    tmp[threadIdx.x] = v;
    __syncthreads();
    for (int o = 1; o < SCAN_B; o <<= 1) {
        int t = (threadIdx.x >= o) ? tmp[threadIdx.x - o] : 0;
        __syncthreads();
        tmp[threadIdx.x] += t;
        __syncthreads();
    }
    if (threadIdx.x < nb) bsum[threadIdx.x] = tmp[threadIdx.x] - v;
}

__global__ __launch_bounds__(SCAN_B) void scan3_kernel(int* __restrict__ exc, const int* __restrict__ bsum,
                                                       int* __restrict__ cursor, int n, int E) {
    int i = blockIdx.x * SCAN_B + threadIdx.x;
    if (i < n) {
        int v = exc[i] + bsum[blockIdx.x];
        exc[i] = v;
        cursor[i] = v;
    }
    if (i == n) exc[n] = E;
}

// 8-cohort scatter: block (blockIdx&7)==q handles node range q only. With round-robin
// block->XCD dispatch, range q's es region (800KB) is written by one XCD's L2 ->
// full-line writebacks instead of 16x-amplified partial lines.
#define NCB 256

__global__ __launch_bounds__(256) void scatter8_kernel(const int* __restrict__ src, const int* __restrict__ dst,
                                                       int* __restrict__ cursor, int* __restrict__ es, int E, int n) {
    int q = blockIdx.x & 7;
    int cb = blockIdx.x >> 3;
    int lo = q * (n >> 3);
    int hi = (q == 7) ? n : lo + (n >> 3);
    int chunk = (E + NCB - 1) / NCB;
    int e1 = min((cb + 1) * chunk, E);
    for (int e = cb * chunk + threadIdx.x; e < e1; e += 256) {
        int d = dst[e];
        if (d >= lo && d < hi) {
            int pos = atomicAdd(&cursor[d], 1);
            es[pos] = src[e];
        }
    }
}

// ---------------- W pre-split ----------------

__global__ __launch_bounds__(256) void wsplit_kernel(const float* __restrict__ W, short* __restrict__ WhT,
                                                     short* __restrict__ WlT, int K, int C) {
    int f = blockIdx.x * 256 + threadIdx.x;
    if (f >= K * C) return;
    int k = f / C, c = f % C;
    float v = W[f];
    short h = f2bf(v);
    short l = f2bf(v - bf2f(h));
    WhT[(size_t)c * K + k] = h;
    WlT[(size_t)c * K + k] = l;
}

// ---------------- fp32 -> fp16 table convert ----------------

__global__ __launch_bounds__(256) void tohalf_kernel(const float* __restrict__ in, __half* __restrict__ out,
                                                     size_t cnt) {
    size_t i = (size_t)(blockIdx.x * 256 + threadIdx.x) * 4;
    if (i + 3 < cnt) {
        float4 v = *(const float4*)(in + i);
        __half h0 = __float2half(v.x), h1 = __float2half(v.y);
        __half h2 = __float2half(v.z), h3 = __float2half(v.w);
        __half2* op = (__half2*)(out + i);
        op[0] = __half2(h0, h1);
        op[1] = __half2(h2, h3);
    }
}

// ---------------- split-bf16 MFMA GEMM (+fused dots, optional fp16 output) ----------------

template <bool BRELU, bool DOTS, bool HOUT>
__global__ __launch_bounds__(256) void gemm_mfma_kernel(const float* __restrict__ X, const short* __restrict__ BhT,
                                                        const short* __restrict__ BlT, const float* __restrict__ bias,
                                                        float* __restrict__ out, const float* __restrict__ a1v,
                                                        const float* __restrict__ a2v, float* __restrict__ s1,
                                                        float* __restrict__ s2, int n, int K, int Cout) {
    __shared__ short Ah[128][40], Al[128][40];
    __shared__ short Bh[128][40], Bl[128][40];
    int tid = threadIdx.x;
    int row0 = blockIdx.y * 128, col0 = blockIdx.x * 128;
    int lane = tid & 63, wid = tid >> 6;
    int wr = (wid >> 1) * 64, wc = (wid & 1) * 64;

    f32x4 acc[4][4];
#pragma unroll
    for (int mi = 0; mi < 4; ++mi)
#pragma unroll
        for (int ni = 0; ni < 4; ++ni) acc[mi][ni] = 0.f;

    int srow = tid >> 1;
    int sk = (tid & 1) * 16;

    for (int k0 = 0; k0 < K; k0 += 32) {
        {
            float v[16];
            int gr = row0 + srow;
            if (gr < n) {
                const float* p = X + (size_t)gr * K + k0 + sk;
                float4 f0 = ((const float4*)p)[0];
                float4 f1 = ((const float4*)p)[1];
                float4 f2 = ((const float4*)p)[2];
                float4 f3 = ((const float4*)p)[3];
                v[0] = f0.x; v[1] = f0.y; v[2] = f0.z; v[3] = f0.w;
                v[4] = f1.x; v[5] = f1.y; v[6] = f1.z; v[7] = f1.w;
                v[8] = f2.x; v[9] = f2.y; v[10] = f2.z; v[11] = f2.w;
                v[12] = f3.x; v[13] = f3.y; v[14] = f3.z; v[15] = f3.w;
            } else {
#pragma unroll
                for (int j = 0; j < 16; ++j) v[j] = 0.f;
            }
            short8 h0, h1, l0, l1;
#pragma unroll
            for (int j = 0; j < 8; ++j) {
                short h = f2bf(v[j]);
                h0[j] = h;
                l0[j] = f2bf(v[j] - bf2f(h));
            }
#pragma unroll
            for (int j = 0; j < 8; ++j) {
                short h = f2bf(v[8 + j]);
                h1[j] = h;
                l1[j] = f2bf(v[8 + j] - bf2f(h));
            }
            *(short8*)&Ah[srow][sk] = h0;
            *(short8*)&Ah[srow][sk + 8] = h1;
            *(short8*)&Al[srow][sk] = l0;
            *(short8*)&Al[srow][sk + 8] = l1;
        }
        {
            const short* ph = BhT + (size_t)(col0 + srow) * K + k0 + sk;
            const short* pl = BlT + (size_t)(col0 + srow) * K + k0 + sk;
            short8 bh0 = ((const short8*)ph)[0];
            short8 bh1 = ((const short8*)ph)[1];
            short8 bl0 = ((const short8*)pl)[0];
            short8 bl1 = ((const short8*)pl)[1];
            *(short8*)&Bh[srow][sk] = bh0;
            *(short8*)&Bh[srow][sk + 8] = bh1;
            *(short8*)&Bl[srow][sk] = bl0;
            *(short8*)&Bl[srow][sk + 8] = bl1;
        }
        __syncthreads();

        int fr = lane & 15, kb = lane >> 4;
        short8 a_h[4], a_l[4];
#pragma unroll
        for (int mi = 0; mi < 4; ++mi) {
            a_h[mi] = *(const short8*)&Ah[wr + mi * 16 + fr][kb * 8];
            a_l[mi] = *(const short8*)&Al[wr + mi * 16 + fr][kb * 8];
        }
#pragma unroll
        for (int ni = 0; ni < 4; ++ni) {
            short8 b_h = *(const short8*)&Bh[wc + ni * 16 + fr][kb * 8];
            short8 b_l = *(const short8*)&Bl[wc + ni * 16 + fr][kb * 8];
#pragma unroll
            for (int mi = 0; mi < 4; ++mi) {
                acc[mi][ni] = __builtin_amdgcn_mfma_f32_16x16x32_bf16(a_l[mi], b_h, acc[mi][ni], 0, 0, 0);
                acc[mi][ni] = __builtin_amdgcn_mfma_f32_16x16x32_bf16(a_h[mi], b_l, acc[mi][ni], 0, 0, 0);
                acc[mi][ni] = __builtin_amdgcn_mfma_f32_16x16x32_bf16(a_h[mi], b_h, acc[mi][ni], 0, 0, 0);
            }
        }
        __syncthreads();
    }

    int dc = lane & 15, dr = (lane >> 4) * 4;

    if (DOTS) {
#pragma unroll
        for (int mi = 0; mi < 4; ++mi) {
#pragma unroll
            for (int r = 0; r < 4; ++r) {
                float p1 = 0.f, p2 = 0.f;
#pragma unroll
                for (int ni = 0; ni < 4; ++ni) {
                    int gcol = col0 + wc + ni * 16 + dc;
                    float v = acc[mi][ni][r];
                    p1 = fmaf(v, a1v[gcol], p1);
                    p2 = fmaf(v, a2v[gcol], p2);
                }
#pragma unroll
                for (int o = 8; o; o >>= 1) {
                    p1 += __shfl_xor(p1, o, 64);
                    p2 += __shfl_xor(p2, o, 64);
                }
                int grow = row0 + wr + mi * 16 + dr + r;
                if (dc == 0 && grow < n) {
                    atomicAdd(s1 + grow, p1);
                    atomicAdd(s2 + grow, p2);
                }
            }
        }
    }

#pragma unroll
    for (int mi = 0; mi < 4; ++mi) {
#pragma unroll
        for (int r = 0; r < 4; ++r) {
            int grow = row0 + wr + mi * 16 + dr + r;
            if (grow >= n) continue;
#pragma unroll
            for (int ni = 0; ni < 4; ++ni) {
                int gcol = col0 + wc + ni * 16 + dc;
                float v = acc[mi][ni][r];
                if (BRELU) {
                    v += bias[gcol];
                    v = fmaxf(v, 0.f);
                }
                if (HOUT) {
                    ((__half*)out)[(size_t)grow * Cout + gcol] = __float2half(v);
                } else {
                    out[(size_t)grow * Cout + gcol] = v;
                }
            }
        }
    }
}

// ---------------- per-row dual dot (layer-1 only) ----------------

__global__ __launch_bounds__(256) void rowdots_kernel(const float* __restrict__ H, const float* __restrict__ a1,
                                                      const float* __restrict__ a2, float* __restrict__ s1,
                                                      float* __restrict__ s2, int n, int C) {
    int w = (blockIdx.x * 256 + threadIdx.x) >> 6;
    int lane = threadIdx.x & 63;
    if (w >= n) return;
    const float* hp = H + (size_t)w * C;
    float acc1 = 0.f, acc2 = 0.f;
    for (int c = lane; c < C; c += 64) {
        float hv = hp[c];
        acc1 = fmaf(hv, a1[c], acc1);
        acc2 = fmaf(hv, a2[c], acc2);
    }
#pragma unroll
    for (int o = 32; o; o >>= 1) {
        acc1 += __shfl_xor(acc1, o, 64);
        acc2 += __shfl_xor(acc2, o, 64);
    }
    if (lane == 0) {
        s1[w] = acc1;
        s2[w] = acc2;
    }
}

// ---------------- fused aggregation: softmax prep + gather, 1 wave/node ----------------
// VPL = C/64 fp16 cols per lane (4 for C=256 via 8B load, 2 for C=128 via 4B load).

template <int C, bool RELU, bool SOFTMAX>
__global__ __launch_bounds__(256) void aggf_kernel(const __half* __restrict__ H, const float* __restrict__ ssrc,
                                                   const float* __restrict__ sdst, const int* __restrict__ off,
                                                   const int* __restrict__ es, const float* __restrict__ bias,
                                                   float* __restrict__ out, int n) {
    constexpr int VPL = C / 64;
    int wid = threadIdx.x >> 6, lane = threadIdx.x & 63;
    int node = blockIdx.x * 4 + wid;
    if (node >= n) return;
    int beg = off[node], end = off[node + 1];
    float sd = sdst[node];

    // pass 1: segment max of leaky_relu logits (ssrc is L2-resident, 200KB)
    float m = -3e38f;
    for (int e = beg + lane; e < end; e += 64) {
        float g = ssrc[es[e]] + sd;
        g = (g > 0.f) ? g : 0.2f * g;
        m = fmaxf(m, g);
    }
#pragma unroll
    for (int o = 32; o; o >>= 1) m = fmaxf(m, __shfl_xor(m, o, 64));

    // pass 2: p = exp(g-m); den += p; acc += p * H[src] (unnormalized)
    float acc[VPL];
#pragma unroll
    for (int v = 0; v < VPL; ++v) acc[v] = 0.f;
    float den = 0.f;
    int c0 = lane * VPL;

    for (int base = beg; base < end; base += 64) {
        int e = base + lane;
        float p = 0.f;
        int s = 0;
        if (e < end) {
            s = es[e];
            float g = ssrc[s] + sd;
            g = (g > 0.f) ? g : 0.2f * g;
            p = __expf(g - m);
            den += p;
        }
        int cnt = end - base;
        if (cnt > 64) cnt = 64;
        int j0 = 0;
        for (; j0 + 8 <= cnt; j0 += 8) {
            float pj[8];
            const __half* hp[8];
#pragma unroll
            for (int u = 0; u < 8; ++u) {
                pj[u] = __shfl(p, j0 + u, 64);
                int sj = __shfl(s, j0 + u, 64);
                hp[u] = H + (size_t)sj * C + c0;
            }
            if (VPL == 4) {
                uint2 raw[8];
#pragma unroll
                for (int u = 0; u < 8; ++u) raw[u] = *(const uint2*)hp[u];
#pragma unroll
                for (int u = 0; u < 8; ++u) {
                    union { unsigned u32; __half2 h2; } lo, hi;
                    lo.u32 = raw[u].x;
                    hi.u32 = raw[u].y;
                    float2 f0 = __half22float2(lo.h2);
                    float2 f1 = __half22float2(hi.h2);
                    acc[0] = fmaf(pj[u], f0.x, acc[0]);
                    acc[1] = fmaf(pj[u], f0.y, acc[1]);
                    acc[2] = fmaf(pj[u], f1.x, acc[2]);
                    acc[3] = fmaf(pj[u], f1.y, acc[3]);
                }
            } else {
                __half2 hv[8];
#pragma unroll
                for (int u = 0; u < 8; ++u) hv[u] = *(const __half2*)hp[u];
#pragma unroll
                for (int u = 0; u < 8; ++u) {
                    float2 f = __half22float2(hv[u]);
                    acc[0] = fmaf(pj[u], f.x, acc[0]);
                    acc[1] = fmaf(pj[u], f.y, acc[1]);
                }
            }
        }
        for (; j0 < cnt; ++j0) {
            float pj = __shfl(p, j0, 64);
            int sj = __shfl(s, j0, 64);
            const __half* hp = H + (size_t)sj * C + c0;
            if (VPL == 4) {
                uint2 raw = *(const uint2*)hp;
                union { unsigned u32; __half2 h2; } lo, hi;
                lo.u32 = raw.x;
                hi.u32 = raw.y;
                float2 f0 = __half22float2(lo.h2);
                float2 f1 = __half22float2(hi.h2);
                acc[0] = fmaf(pj, f0.x, acc[0]);
                acc[1] = fmaf(pj, f0.y, acc[1]);
                acc[2] = fmaf(pj, f1.x, acc[2]);
                acc[3] = fmaf(pj, f1.y, acc[3]);
            } else {
                float2 f = __half22float2(*(const __half2*)hp);
                acc[0] = fmaf(pj, f.x, acc[0]);
                acc[1] = fmaf(pj, f.y, acc[1]);
            }
        }
    }

#pragma unroll
    for (int o = 32; o; o >>= 1) den += __shfl_xor(den, o, 64);
    float inv = (den > 0.f) ? 1.f / den : 0.f;

    float ov[VPL];
#pragma unroll
    for (int v = 0; v < VPL; ++v) {
        float bb = bias ? bias[c0 + v] : 0.f;
        ov[v] = fmaf(acc[v], inv, bb);
        if (RELU) ov[v] = fmaxf(ov[v], 0.f);
    }
    if (SOFTMAX) {
        float mm = ov[0];
#pragma unroll
        for (int v = 1; v < VPL; ++v) mm = fmaxf(mm, ov[v]);
#pragma unroll
        for (int o = 32; o; o >>= 1) mm = fmaxf(mm, __shfl_xor(mm, o, 64));
        float ss = 0.f;
#pragma unroll
        for (int v = 0; v < VPL; ++v) {
            ov[v] = __expf(ov[v] - mm);
            ss += ov[v];
        }
#pragma unroll
        for (int o = 32; o; o >>= 1) ss += __shfl_xor(ss, o, 64);
        float si = 1.f / ss;
#pragma unroll
        for (int v = 0; v < VPL; ++v) ov[v] *= si;
    }
    float* op = out + (size_t)node * C + c0;
    if (VPL == 4)
        *(float4*)op = make_float4(ov[0], ov[1], ov[2], ov[3]);
    else
        *(float2*)op = make_float2(ov[0], ov[1]);
}

// ---------------- launch ----------------

extern "C" void kernel_launch(void* const* d_in, const int* in_sizes, int n_in,
                              void* d_out, int out_size, void* d_ws, size_t ws_size,
                              hipStream_t stream) {
    const float* x = (const float*)d_in[0];
    const int* ei = (const int*)d_in[1];
    const float* W1 = (const float*)d_in[2];
    const float* a1s = (const float*)d_in[3];
    const float* a1d = (const float*)d_in[4];
    const float* b1 = (const float*)d_in[5];
    const float* W2 = (const float*)d_in[6];
    const float* a2s = (const float*)d_in[7];
    const float* a2d = (const float*)d_in[8];
    const float* b2 = (const float*)d_in[9];
    const float* W3 = (const float*)d_in[10];
    const float* a3s = (const float*)d_in[11];
    const float* a3d = (const float*)d_in[12];
    const float* b3 = (const float*)d_in[13];

    const int n = NN, E = EE;
    const int* src = ei;
    const int* dst = ei + E;

    char* base = (char*)d_ws;
    size_t o = 0;
    auto alloc = [&](size_t bytes) -> char* {
        char* p = base + o;
        o += (bytes + 255) & ~(size_t)255;
        return p;
    };
    int* off = (int*)alloc((n + 1) * sizeof(int));
    int* cur = (int*)alloc((n + 1) * sizeof(int));
    int* bsum = (int*)alloc(1024 * sizeof(int));
    int* es = (int*)alloc((size_t)E * sizeof(int));
    float* sbuf = (float*)alloc((size_t)2 * n * sizeof(float));  // ssrc | sdst
    float* ssrc = sbuf;
    float* sdst = sbuf + n;
    float* was = (float*)alloc(256 * sizeof(float));
    float* wad = (float*)alloc(256 * sizeof(float));
    short* W1h = (short*)alloc((size_t)DIN * HH * sizeof(short));
    short* W1l = (short*)alloc((size_t)DIN * HH * sizeof(short));
    short* W2h = (short*)alloc((size_t)HH * HH * sizeof(short));
    short* W2l = (short*)alloc((size_t)HH * HH * sizeof(short));
    short* W3h = (short*)alloc((size_t)HH * DOUT * sizeof(short));
    short* W3l = (short*)alloc((size_t)HH * DOUT * sizeof(short));
    __half* xh = (__half*)alloc((size_t)n * DIN * sizeof(__half));
    __half* Hh = (__half*)alloc((size_t)n * HH * sizeof(__half));
    float* Hbuf = (float*)alloc((size_t)n * HH * sizeof(float));
    float* Abuf = (float*)alloc((size_t)n * HH * sizeof(float));
    (void)ws_size;

    // --- CSR build (grouped by dst) ---
    hipMemsetAsync(cur, 0, (n + 1) * sizeof(int), stream);
    hist_kernel<<<(E + 255) / 256, 256, 0, stream>>>(dst, cur, E);
    int nb = (n + SCAN_B - 1) / SCAN_B;
    scan1_kernel<<<nb, SCAN_B, 0, stream>>>(cur, off, bsum, n);
    scan2_kernel<<<1, SCAN_B, 0, stream>>>(bsum, nb);
    scan3_kernel<<<nb, SCAN_B, 0, stream>>>(off, bsum, cur, n, E);
    scatter8_kernel<<<NCB * 8, 256, 0, stream>>>(src, dst, cur, es, E, n);

    // --- W splits + X fp16 copy ---
    wsplit_kernel<<<(DIN * HH + 255) / 256, 256, 0, stream>>>(W1, W1h, W1l, DIN, HH);
    wsplit_kernel<<<(HH * HH + 255) / 256, 256, 0, stream>>>(W2, W2h, W2l, HH, HH);
    wsplit_kernel<<<(HH * DOUT + 255) / 256, 256, 0, stream>>>(W3, W3h, W3l, HH, DOUT);
    tohalf_kernel<<<((n * DIN / 4) + 255) / 256, 256, 0, stream>>>(x, xh, (size_t)n * DIN);

    int wgrid = (n * 64 + 255) / 256;
    int agrid = (n + 3) / 4;
    int rb = (n + 127) / 128;

    // --- layer 1, reordered: logits via X@(W1 a); Z = A-hat X (fp16 gather, C=128); A1 = relu(Z W1 + b1) ---
    {
        rowdots_kernel<<<(128 * 64 + 255) / 256, 256, 0, stream>>>(W1, a1s, a1d, was, wad, DIN, HH);
        rowdots_kernel<<<wgrid, 256, 0, stream>>>(x, was, wad, ssrc, sdst, n, DIN);
        aggf_kernel<DIN, false, false><<<agrid, 256, 0, stream>>>(xh, ssrc, sdst, off, es, nullptr, Hbuf, n);
        dim3 g(HH / 128, rb);
        gemm_mfma_kernel<true, false, false><<<g, 256, 0, stream>>>(Hbuf, W1h, W1l, b1, Abuf, nullptr, nullptr,
                                                                    nullptr, nullptr, n, DIN, HH);
    }
    // --- layers 2,3 (shared W2): gemm(fp16 H out + fused dots), fused agg ---
    for (int t = 0; t < 2; ++t) {
        dim3 g(HH / 128, rb);
        hipMemsetAsync(sbuf, 0, (size_t)2 * n * sizeof(float), stream);
        gemm_mfma_kernel<false, true, true><<<g, 256, 0, stream>>>(Abuf, W2h, W2l, nullptr, (float*)Hh, a2s, a2d,
                                                                   ssrc, sdst, n, HH, HH);
        aggf_kernel<HH, true, false><<<agrid, 256, 0, stream>>>(Hh, ssrc, sdst, off, es, b2, Abuf, n);
    }
    // --- layer 4: gemm(fp16 H out + fused dots), fused agg + in-wave feature softmax -> d_out ---
    {
        dim3 g(DOUT / 128, rb);
        hipMemsetAsync(sbuf, 0, (size_t)2 * n * sizeof(float), stream);
        gemm_mfma_kernel<false, true, true><<<g, 256, 0, stream>>>(Abuf, W3h, W3l, nullptr, (float*)Hh, a3s, a3d,
                                                                   ssrc, sdst, n, HH, DOUT);
        aggf_kernel<DOUT, false, true><<<agrid, 256, 0, stream>>>(Hh, ssrc, sdst, off, es, b3, (float*)d_out, n);
    }
}